// Round 1
// baseline (1147.511 us; speedup 1.0000x reference)
//
#include <hip/hip_runtime.h>

#define NN 20000      // nodes
#define NE 200000     // edges
#define NH1 256       // H*C layer1
#define ED 384
#define NG 64
#define NCLS 751
#define ETOT (NE + NN)   // 220000 edges incl self loops

typedef unsigned short u16;
typedef __attribute__((ext_vector_type(8))) short short8;
typedef __attribute__((ext_vector_type(4))) float f32x4;

__device__ __forceinline__ float bf2f(u16 u){
  union { unsigned int i; float f; } v; v.i = ((unsigned int)u) << 16; return v.f;
}
__device__ __forceinline__ u16 f2bf(float f){
  union { float f; unsigned int i; } v; v.f = f;
  return (u16)((v.i + 0x7fffu + ((v.i >> 16) & 1u)) >> 16);
}

// ---------- prep kernels ----------
// transpose + f32->bf16: in [K,N] f32 row-major -> out [N,K] bf16
__global__ void transpose_k(const float* __restrict__ in, u16* __restrict__ out, int K, int N){
  int idx = blockIdx.x * 256 + threadIdx.x;
  if (idx >= K * N) return;
  int k = idx / N, n = idx - k * N;
  out[n * K + k] = f2bf(in[idx]);
}

__global__ void concatbias_k(const float* __restrict__ b1l, const float* __restrict__ b1r,
                             const float* __restrict__ b2l, const float* __restrict__ b2r,
                             float* __restrict__ biasLR1, float* __restrict__ biasLR2){
  int i = blockIdx.x * 256 + threadIdx.x;
  if (i < 256) biasLR1[i] = b1l[i];
  else if (i < 512) biasLR1[i] = b1r[i - 256];
  else if (i < 576) biasLR2[i - 512] = b2l[i - 512];
  else if (i < 640) biasLR2[i - 512] = b2r[i - 576];
}

__global__ void hist_k(const int* __restrict__ rowA, const int* __restrict__ colA,
                       int* __restrict__ degR, int* __restrict__ degC){
  int e = blockIdx.x * 256 + threadIdx.x;
  if (e >= NE) return;
  atomicAdd(&degR[rowA[e]], 1);
  atomicAdd(&degC[colA[e]], 1);
}

__global__ void scan_k(const int* __restrict__ degR, const int* __restrict__ degC,
                       int* __restrict__ rowPtr, int* __restrict__ colPtr){
  __shared__ int sR[256], sC[256];
  int t = threadIdx.x;
  const int chunk = (NN + 255) / 256;
  int beg = t * chunk, end = min(beg + chunk, NN);
  int aR = 0, aC = 0;
  for (int i = beg; i < end; i++){ aR += degR[i]; aC += degC[i]; }
  sR[t] = aR; sC[t] = aC;
  __syncthreads();
  for (int off = 1; off < 256; off <<= 1){
    int vR = 0, vC = 0;
    if (t >= off){ vR = sR[t - off]; vC = sC[t - off]; }
    __syncthreads();
    sR[t] += vR; sC[t] += vC;
    __syncthreads();
  }
  int rR = (t == 0) ? 0 : sR[t - 1];
  int rC = (t == 0) ? 0 : sC[t - 1];
  for (int i = beg; i < end; i++){
    rowPtr[i] = rR; rR += degR[i];
    colPtr[i] = rC; rC += degC[i];
  }
  if (t == 255){ rowPtr[NN] = sR[255]; colPtr[NN] = sC[255]; }
}

__global__ void scatter_k(const int* __restrict__ rowA, const int* __restrict__ colA,
                          const int* __restrict__ rowPtr, const int* __restrict__ colPtr,
                          int* __restrict__ rowCur, int* __restrict__ colCur,
                          int* __restrict__ rowIdx, int* __restrict__ colIdx){
  int e = blockIdx.x * 256 + threadIdx.x;
  if (e >= NE) return;
  int r = rowA[e]; int p = atomicAdd(&rowCur[r], 1); rowIdx[rowPtr[r] + p] = e;
  int c = colA[e]; int q = atomicAdd(&colCur[c], 1); colIdx[colPtr[c] + q] = e;
}

// loop_attr[n] = mean over incoming (col) edges of edge_attr -> bf16
__global__ __launch_bounds__(256) void loopattr_k(const int* __restrict__ colPtr,
                                                  const int* __restrict__ colIdx,
                                                  const float* __restrict__ eattr,
                                                  u16* __restrict__ loopA16){
  int node = blockIdx.x * 4 + (threadIdx.x >> 6);
  if (node >= NN) return;
  int lane = threadIdx.x & 63;
  int p0 = colPtr[node], deg = colPtr[node + 1] - p0;
  float inv = 1.f / fmaxf((float)deg, 1.f);
  float s[6] = {0.f, 0.f, 0.f, 0.f, 0.f, 0.f};
  for (int t = 0; t < deg; t++){
    const float* rowp = eattr + (size_t)colIdx[p0 + t] * ED;
    #pragma unroll
    for (int c0 = 0; c0 < 6; c0++) s[c0] += rowp[c0 * 64 + lane];
  }
  u16* outp = loopA16 + (size_t)node * ED;
  #pragma unroll
  for (int c0 = 0; c0 < 6; c0++) outp[c0 * 64 + lane] = f2bf(s[c0] * inv);
}

// ---------- generic node GEMM (mode-0 only): C[M,Ntot] = A[M,K] x B, bf16 out + f32 bias
// Software-pipelined: next k-tile is register-prefetched during the MFMA phase so the
// vmcnt(0) drain at the trailing __syncthreads() lands after ~a full compute phase.
__global__ __launch_bounds__(256)
void gemm_k(const void* __restrict__ Av, int aF32,
            const u16* __restrict__ Bt, int M, int K, int Ntot,
            const float* __restrict__ bias, u16* __restrict__ outBf)
{
  __shared__ __align__(16) u16 lA[128 * 40];
  __shared__ __align__(16) u16 lB[64 * 40];
  const int tid  = threadIdx.x;
  const int lane = tid & 63;
  const int wave = tid >> 6;
  const int m0 = blockIdx.x * 128;
  const int n0 = blockIdx.y * 64;
  const int lr  = tid >> 2;
  const int lkc = (tid & 3) << 3;
  const int lm = lane & 15;
  const int lk = (lane >> 4) << 3;
  const int wrow = wave << 5;

  f32x4 acc[2][4];
  #pragma unroll
  for (int i = 0; i < 2; i++)
    #pragma unroll
    for (int j = 0; j < 4; j++) acc[i][j] = (f32x4){0.f, 0.f, 0.f, 0.f};

  const int gm0 = m0 + lr;
  const int gm1 = m0 + lr + 64;

  // prefetch registers
  float4 fa[2][2];
  uint4  hA[2];
  uint4  hB;

  auto ISSUE = [&](int k0){
    if (aF32){
      if (gm0 < M){
        const float* s = (const float*)Av + (size_t)gm0 * K + k0 + lkc;
        fa[0][0] = *(const float4*)s; fa[0][1] = *(const float4*)(s + 4);
      }
      if (gm1 < M){
        const float* s = (const float*)Av + (size_t)gm1 * K + k0 + lkc;
        fa[1][0] = *(const float4*)s; fa[1][1] = *(const float4*)(s + 4);
      }
    } else {
      if (gm0 < M) hA[0] = *(const uint4*)((const u16*)Av + (size_t)gm0 * K + k0 + lkc);
      if (gm1 < M) hA[1] = *(const uint4*)((const u16*)Av + (size_t)gm1 * K + k0 + lkc);
    }
    hB = *(const uint4*)(Bt + (size_t)(n0 + lr) * K + k0 + lkc);
  };

  auto STORE = [&](){
    union { u16 h[8]; uint4 v; } p0, p1;
    p0.v = make_uint4(0u, 0u, 0u, 0u);
    p1.v = make_uint4(0u, 0u, 0u, 0u);
    if (aF32){
      if (gm0 < M){
        p0.h[0] = f2bf(fa[0][0].x); p0.h[1] = f2bf(fa[0][0].y);
        p0.h[2] = f2bf(fa[0][0].z); p0.h[3] = f2bf(fa[0][0].w);
        p0.h[4] = f2bf(fa[0][1].x); p0.h[5] = f2bf(fa[0][1].y);
        p0.h[6] = f2bf(fa[0][1].z); p0.h[7] = f2bf(fa[0][1].w);
      }
      if (gm1 < M){
        p1.h[0] = f2bf(fa[1][0].x); p1.h[1] = f2bf(fa[1][0].y);
        p1.h[2] = f2bf(fa[1][0].z); p1.h[3] = f2bf(fa[1][0].w);
        p1.h[4] = f2bf(fa[1][1].x); p1.h[5] = f2bf(fa[1][1].y);
        p1.h[6] = f2bf(fa[1][1].z); p1.h[7] = f2bf(fa[1][1].w);
      }
    } else {
      if (gm0 < M) p0.v = hA[0];
      if (gm1 < M) p1.v = hA[1];
    }
    *(uint4*)(&lA[lr * 40 + lkc]) = p0.v;
    *(uint4*)(&lA[(lr + 64) * 40 + lkc]) = p1.v;
    *(uint4*)(&lB[lr * 40 + lkc]) = hB;
  };

  ISSUE(0);
  for (int k0 = 0; k0 < K; k0 += 32){
    STORE();
    __syncthreads();                 // writes visible; nothing of ours in flight yet
    if (k0 + 32 < K) ISSUE(k0 + 32); // next tile in flight across the MFMA phase
    short8 a0 = *(const short8*)(&lA[(wrow + lm) * 40 + lk]);
    short8 a1 = *(const short8*)(&lA[(wrow + 16 + lm) * 40 + lk]);
    #pragma unroll
    for (int nj = 0; nj < 4; nj++){
      short8 b = *(const short8*)(&lB[(nj * 16 + lm) * 40 + lk]);
      acc[0][nj] = __builtin_amdgcn_mfma_f32_16x16x32_bf16(a0, b, acc[0][nj], 0, 0, 0);
      acc[1][nj] = __builtin_amdgcn_mfma_f32_16x16x32_bf16(a1, b, acc[1][nj], 0, 0, 0);
    }
    __syncthreads();                 // drains vmcnt(0) — prefetch had the MFMA phase to land
  }

  #pragma unroll
  for (int mi = 0; mi < 2; mi++)
    #pragma unroll
    for (int r4 = 0; r4 < 4; r4++){
      int row = wrow + mi * 16 + ((lane >> 4) << 2) + r4;
      int gm = m0 + row;
      if (gm < M){
        #pragma unroll
        for (int nj = 0; nj < 4; nj++){
          int gc = n0 + nj * 16 + lm;
          outBf[(size_t)gm * Ntot + gc] = f2bf(acc[mi][nj][r4] + bias[gc]);
        }
      }
    }
}

// ---------- fused edge GEMM: ea[ETOT,384] x [W1e|W2e][384,320] ----------
// wave w: head-w 64 cols (logit1 epilogue) + 16-col slice of ep2 (cols 256..319)
// Software-pipelined staging (see gemm_k comment).
__global__ __launch_bounds__(256)
void edge_k(const float* __restrict__ eattr, const u16* __restrict__ loopA16,
            const u16* __restrict__ BtE,     // [320 x 384] bf16
            const int* __restrict__ rowA, const int* __restrict__ colA,
            const u16* __restrict__ XLR1,    // [NN x 512] bf16 = [xl1 | xr1]
            const float* __restrict__ att1,  // [256] f32
            float* __restrict__ logit1,      // [ETOT x 4] f32
            u16* __restrict__ ep2)           // [ETOT x 64] bf16
{
  __shared__ __align__(16) u16 lA[64 * 40];
  __shared__ __align__(16) u16 lB[320 * 40];
  const int tid = threadIdx.x;
  const int lane = tid & 63;
  const int wave = tid >> 6;            // head 0..3
  const int m0 = blockIdx.x * 64;
  const int lm = lane & 15;
  const int lk = (lane >> 4) << 3;
  const int arow = tid >> 2;            // 0..63
  const int akc = (tid & 3) << 3;       // 0,8,16,24

  f32x4 acc[4][5];
  #pragma unroll
  for (int i = 0; i < 4; i++)
    #pragma unroll
    for (int j = 0; j < 5; j++) acc[i][j] = (f32x4){0.f, 0.f, 0.f, 0.f};

  const int gmA = m0 + arow;

  // prefetch registers: A row (f32 or bf16 loop row) + 5 B rows
  float4 fa0, fa1;
  uint4  hA;
  uint4  hB[5];

  auto ISSUE = [&](int k0){
    if (gmA < NE){
      const float* s = eattr + (size_t)gmA * ED + k0 + akc;
      fa0 = *(const float4*)s;
      fa1 = *(const float4*)(s + 4);
    } else if (gmA < ETOT){
      hA = *(const uint4*)(loopA16 + (size_t)(gmA - NE) * ED + k0 + akc);
    }
    #pragma unroll
    for (int rr = 0; rr < 5; rr++)
      hB[rr] = *(const uint4*)(BtE + (size_t)(arow + rr * 64) * ED + k0 + akc);
  };

  auto STORE = [&](){
    union { u16 h[8]; uint4 v; } pk;
    pk.v = make_uint4(0u, 0u, 0u, 0u);
    if (gmA < NE){
      pk.h[0] = f2bf(fa0.x); pk.h[1] = f2bf(fa0.y); pk.h[2] = f2bf(fa0.z); pk.h[3] = f2bf(fa0.w);
      pk.h[4] = f2bf(fa1.x); pk.h[5] = f2bf(fa1.y); pk.h[6] = f2bf(fa1.z); pk.h[7] = f2bf(fa1.w);
    } else if (gmA < ETOT){
      pk.v = hA;
    }
    *(uint4*)(&lA[arow * 40 + akc]) = pk.v;
    #pragma unroll
    for (int rr = 0; rr < 5; rr++)
      *(uint4*)(&lB[(arow + rr * 64) * 40 + akc]) = hB[rr];
  };

  ISSUE(0);
  for (int k0 = 0; k0 < ED; k0 += 32){
    STORE();
    __syncthreads();                    // stage visible to all waves
    if (k0 + 32 < ED) ISSUE(k0 + 32);   // next tile in flight across MFMA phase
    short8 a[4];
    #pragma unroll
    for (int mi = 0; mi < 4; mi++) a[mi] = *(const short8*)(&lA[(mi * 16 + lm) * 40 + lk]);
    #pragma unroll
    for (int nj = 0; nj < 4; nj++){
      short8 b = *(const short8*)(&lB[(wave * 64 + nj * 16 + lm) * 40 + lk]);
      #pragma unroll
      for (int mi = 0; mi < 4; mi++)
        acc[mi][nj] = __builtin_amdgcn_mfma_f32_16x16x32_bf16(a[mi], b, acc[mi][nj], 0, 0, 0);
    }
    {
      short8 b = *(const short8*)(&lB[(256 + wave * 16 + lm) * 40 + lk]);
      #pragma unroll
      for (int mi = 0; mi < 4; mi++)
        acc[mi][4] = __builtin_amdgcn_mfma_f32_16x16x32_bf16(a[mi], b, acc[mi][4], 0, 0, 0);
    }
    __syncthreads();                    // vmcnt(0) drain lands after the compute phase
  }

  float attc[4];
  #pragma unroll
  for (int nj = 0; nj < 4; nj++) attc[nj] = att1[wave * 64 + nj * 16 + lm];
  const int quad4 = (lane >> 4) << 2;
  #pragma unroll
  for (int mi = 0; mi < 4; mi++)
    #pragma unroll
    for (int r4 = 0; r4 < 4; r4++){
      int e = m0 + mi * 16 + quad4 + r4;
      float partial = 0.f;
      if (e < ETOT){
        int ii = (e < NE) ? rowA[e] : (e - NE);
        int jj = (e < NE) ? colA[e] : (e - NE);
        const u16* xlp = XLR1 + (size_t)jj * 512 + wave * 64;
        const u16* xrp = XLR1 + (size_t)ii * 512 + 256 + wave * 64;
        #pragma unroll
        for (int nj = 0; nj < 4; nj++){
          float v = acc[mi][nj][r4] + bf2f(xlp[nj * 16 + lm]) + bf2f(xrp[nj * 16 + lm]);
          v = (v > 0.f) ? v : 0.2f * v;
          partial += v * attc[nj];
        }
        ep2[(size_t)e * 64 + wave * 16 + lm] = f2bf(acc[mi][4][r4]);
      }
      partial += __shfl_xor(partial, 1);
      partial += __shfl_xor(partial, 2);
      partial += __shfl_xor(partial, 4);
      partial += __shfl_xor(partial, 8);
      if (lm == 0 && e < ETOT) logit1[(size_t)e * 4 + wave] = partial;
    }
}

// ---------- layer-2 logit epilogue: logit2[e] = sum_c att2[c]*leaky0.2(ep2+xl2[j]+xr2[i])
__global__ __launch_bounds__(256) void logit2_k(const int* __restrict__ rowA,
    const int* __restrict__ colA, const u16* __restrict__ ep2,
    const u16* __restrict__ XLR2,   // [NN x 128] = [xl2 | xr2]
    const float* __restrict__ att2, float* __restrict__ logit2)
{
  int e = blockIdx.x * 16 + (threadIdx.x >> 4);
  if (e >= ETOT) return;
  int lm = threadIdx.x & 15;
  int ii = (e < NE) ? rowA[e] : (e - NE);
  int jj = (e < NE) ? colA[e] : (e - NE);
  ushort4 pe = *(const ushort4*)(ep2 + (size_t)e * 64 + lm * 4);
  ushort4 pl = *(const ushort4*)(XLR2 + (size_t)jj * 128 + lm * 4);
  ushort4 pr = *(const ushort4*)(XLR2 + (size_t)ii * 128 + 64 + lm * 4);
  float s = 0.f;
  float v0 = bf2f(pe.x) + bf2f(pl.x) + bf2f(pr.x); v0 = v0 > 0.f ? v0 : 0.2f * v0;
  float v1 = bf2f(pe.y) + bf2f(pl.y) + bf2f(pr.y); v1 = v1 > 0.f ? v1 : 0.2f * v1;
  float v2 = bf2f(pe.z) + bf2f(pl.z) + bf2f(pr.z); v2 = v2 > 0.f ? v2 : 0.2f * v2;
  float v3 = bf2f(pe.w) + bf2f(pl.w) + bf2f(pr.w); v3 = v3 > 0.f ? v3 : 0.2f * v3;
  s = v0 * att2[lm * 4] + v1 * att2[lm * 4 + 1] + v2 * att2[lm * 4 + 2] + v3 * att2[lm * 4 + 3];
  s += __shfl_xor(s, 1);
  s += __shfl_xor(s, 2);
  s += __shfl_xor(s, 4);
  s += __shfl_xor(s, 8);
  if (lm == 0) logit2[e] = s;
}

// ---------- segment softmax + aggregation, layer 1 (H=4, C=64) ----------
__global__ __launch_bounds__(256) void agg1_k(const int* __restrict__ rowPtr,
    const int* __restrict__ rowIdx, const float4* __restrict__ lg4,
    const u16* __restrict__ XL1, int xstride, const int* __restrict__ colA,
    const float* __restrict__ bias1, u16* __restrict__ H1)
{
  int node = blockIdx.x * 4 + (threadIdx.x >> 6);
  if (node >= NN) return;
  int lane = threadIdx.x & 63;
  int p0 = rowPtr[node], deg = rowPtr[node + 1] - p0;
  float4 sl = lg4[NE + node];
  float m0 = sl.x, m1 = sl.y, m2 = sl.z, m3 = sl.w;
  for (int t = lane; t < deg; t += 64){
    float4 l = lg4[rowIdx[p0 + t]];
    m0 = fmaxf(m0, l.x); m1 = fmaxf(m1, l.y); m2 = fmaxf(m2, l.z); m3 = fmaxf(m3, l.w);
  }
  #pragma unroll
  for (int off = 32; off > 0; off >>= 1){
    m0 = fmaxf(m0, __shfl_xor(m0, off));
    m1 = fmaxf(m1, __shfl_xor(m1, off));
    m2 = fmaxf(m2, __shfl_xor(m2, off));
    m3 = fmaxf(m3, __shfl_xor(m3, off));
  }
  float d0, d1, d2, d3, a0, a1, a2, a3;
  {
    float e0 = __expf(sl.x - m0), e1 = __expf(sl.y - m1), e2 = __expf(sl.z - m2), e3 = __expf(sl.w - m3);
    d0 = e0; d1 = e1; d2 = e2; d3 = e3;
    const u16* xp = XL1 + (size_t)node * xstride;
    a0 = e0 * bf2f(xp[lane]); a1 = e1 * bf2f(xp[64 + lane]);
    a2 = e2 * bf2f(xp[128 + lane]); a3 = e3 * bf2f(xp[192 + lane]);
  }
  for (int t = 0; t < deg; t++){
    int e = rowIdx[p0 + t];
    float4 l = lg4[e];
    int j = colA[e];
    float e0 = __expf(l.x - m0), e1 = __expf(l.y - m1), e2 = __expf(l.z - m2), e3 = __expf(l.w - m3);
    d0 += e0; d1 += e1; d2 += e2; d3 += e3;
    const u16* xp = XL1 + (size_t)j * xstride;
    a0 += e0 * bf2f(xp[lane]); a1 += e1 * bf2f(xp[64 + lane]);
    a2 += e2 * bf2f(xp[128 + lane]); a3 += e3 * bf2f(xp[192 + lane]);
  }
  float v0 = a0 / d0 + bias1[lane];
  float v1 = a1 / d1 + bias1[64 + lane];
  float v2 = a2 / d2 + bias1[128 + lane];
  float v3 = a3 / d3 + bias1[192 + lane];
  v0 = v0 > 0.f ? v0 : 0.01f * v0;
  v1 = v1 > 0.f ? v1 : 0.01f * v1;
  v2 = v2 > 0.f ? v2 : 0.01f * v2;
  v3 = v3 > 0.f ? v3 : 0.01f * v3;
  u16* hp = H1 + (size_t)node * NH1;
  hp[lane] = f2bf(v0); hp[64 + lane] = f2bf(v1);
  hp[128 + lane] = f2bf(v2); hp[192 + lane] = f2bf(v3);
}

// ---------- layer 2 softmax+agg (H=1, C=64) ----------
__global__ __launch_bounds__(256) void agg2_k(const int* __restrict__ rowPtr,
    const int* __restrict__ rowIdx, const float* __restrict__ lg,
    const u16* __restrict__ XL2, int xstride, const int* __restrict__ colA,
    const float* __restrict__ bias2, float* __restrict__ H2)
{
  int node = blockIdx.x * 4 + (threadIdx.x >> 6);
  if (node >= NN) return;
  int lane = threadIdx.x & 63;
  int p0 = rowPtr[node], deg = rowPtr[node + 1] - p0;
  float sl = lg[NE + node];
  float mx = sl;
  for (int t = lane; t < deg; t += 64) mx = fmaxf(mx, lg[rowIdx[p0 + t]]);
  #pragma unroll
  for (int off = 32; off > 0; off >>= 1) mx = fmaxf(mx, __shfl_xor(mx, off));
  float den = __expf(sl - mx);
  float acc = den * bf2f(XL2[(size_t)node * xstride + lane]);
  for (int t = 0; t < deg; t++){
    int e = rowIdx[p0 + t];
    float ex = __expf(lg[e] - mx);
    den += ex;
    acc += ex * bf2f(XL2[(size_t)colA[e] * xstride + lane]);
  }
  float v = acc / den + bias2[lane];
  v = v > 0.f ? v : 0.01f * v;
  H2[(size_t)node * 64 + lane] = v;
}

// ---------- global max pool + LayerNorm (C=64), 4 waves/block ----------
__global__ __launch_bounds__(256) void poolln_k(const float* __restrict__ H2,
    const float* __restrict__ lng, const float* __restrict__ lnb, float* __restrict__ outGn)
{
  __shared__ float sm[4][64];
  int g = blockIdx.x, w = threadIdx.x >> 6, c = threadIdx.x & 63;
  int beg = (g * NN + NG - 1) / NG;
  int end = ((g + 1) * NN + NG - 1) / NG;
  float m = -3.0e38f;
  for (int n = beg + w; n < end; n += 4) m = fmaxf(m, H2[(size_t)n * 64 + c]);
  sm[w][c] = m;
  __syncthreads();
  if (threadIdx.x < 64){
    m = fmaxf(fmaxf(sm[0][c], sm[1][c]), fmaxf(sm[2][c], sm[3][c]));
    float s = m;
    #pragma unroll
    for (int off = 32; off > 0; off >>= 1) s += __shfl_xor(s, off);
    float mu = s * (1.f / 64.f);
    float d = m - mu;
    float vv = d * d;
    #pragma unroll
    for (int off = 32; off > 0; off >>= 1) vv += __shfl_xor(vv, off);
    float var = vv * (1.f / 64.f);
    outGn[g * 64 + c] = d * rsqrtf(var + 1e-5f) * lng[c] + lnb[c];
  }
}

// ---------- classifier [G,64] @ [64,751] + b ----------
__global__ __launch_bounds__(256) void clf_k(const float* __restrict__ gn,
    const float* __restrict__ W, const float* __restrict__ b, float* __restrict__ outCls)
{
  __shared__ float sg[64];
  int g = blockIdx.x;
  if (threadIdx.x < 64) sg[threadIdx.x] = gn[g * 64 + threadIdx.x];
  __syncthreads();
  for (int o = threadIdx.x; o < NCLS; o += 256){
    float s = b[o];
    #pragma unroll 16
    for (int c = 0; c < 64; c++) s += sg[c] * W[c * NCLS + o];
    outCls[(size_t)g * NCLS + o] = s;
  }
}

extern "C" void kernel_launch(void* const* d_in, const int* in_sizes, int n_in,
                              void* d_out, int out_size, void* d_ws, size_t ws_size,
                              hipStream_t stream)
{
  const float* x     = (const float*)d_in[0];
  const int*   eidx  = (const int*)d_in[1];
  const float* eattr = (const float*)d_in[2];
  const float* W1l = (const float*)d_in[4];
  const float* b1l = (const float*)d_in[5];
  const float* W1r = (const float*)d_in[6];
  const float* b1r = (const float*)d_in[7];
  const float* W1e = (const float*)d_in[8];
  const float* att1 = (const float*)d_in[9];
  const float* bias1 = (const float*)d_in[10];
  const float* W2l = (const float*)d_in[11];
  const float* b2l = (const float*)d_in[12];
  const float* W2r = (const float*)d_in[13];
  const float* b2r = (const float*)d_in[14];
  const float* W2e = (const float*)d_in[15];
  const float* att2 = (const float*)d_in[16];
  const float* bias2 = (const float*)d_in[17];
  const float* lng = (const float*)d_in[18];
  const float* lnb = (const float*)d_in[19];
  const float* clfW = (const float*)d_in[20];
  const float* clfb = (const float*)d_in[21];
  const int* rowA = eidx;        // ei_i (aggregation target)
  const int* colA = eidx + NE;   // ei_j (message source)

  char* w = (char*)d_ws;
  auto alloc = [&](size_t b) -> char* {
    char* p = w; w += (b + 255) & ~(size_t)255; return p;
  };
  u16* W1lrT  = (u16*)alloc((size_t)512 * 512 * 2);   // [512 cols x 512 K]
  u16* BtE    = (u16*)alloc((size_t)320 * ED * 2);    // [W1e|W2e]^T
  u16* W2lrT  = (u16*)alloc((size_t)128 * 256 * 2);
  float* biasLR1 = (float*)alloc(512 * 4);
  float* biasLR2 = (float*)alloc(128 * 4);
  int* degR   = (int*)alloc((size_t)NN * 4);
  int* degC   = (int*)alloc((size_t)NN * 4);
  int* rowPtr = (int*)alloc((size_t)(NN + 1) * 4);
  int* colPtr = (int*)alloc((size_t)(NN + 1) * 4);
  int* rowCur = (int*)alloc((size_t)NN * 4);
  int* colCur = (int*)alloc((size_t)NN * 4);
  int* rowIdx = (int*)alloc((size_t)NE * 4);
  int* colIdx = (int*)alloc((size_t)NE * 4);
  char* loopRegion = alloc((size_t)NN * ED * 2);      // 15.36 MB, reused after edge_k
  u16* loopA16 = (u16*)loopRegion;
  u16* XLR1   = (u16*)alloc((size_t)NN * 512 * 2);
  float* logit1 = (float*)alloc((size_t)ETOT * 4 * 4);
  u16* H1     = (u16*)alloc((size_t)NN * NH1 * 2);
  u16* ep2    = (u16*)alloc((size_t)ETOT * 64 * 2);
  // aliased into loopRegion (loopA16's last reader is edge_k):
  u16* XLR2   = (u16*)loopRegion;                               // 5.12 MB
  float* logit2 = (float*)(loopRegion + (size_t)5500928);       // 0.88 MB
  float* H2   = (float*)(loopRegion + (size_t)6553600);         // 5.12 MB

  hipMemsetAsync(degR, 0, (size_t)NN * 4, stream);
  hipMemsetAsync(degC, 0, (size_t)NN * 4, stream);
  hipMemsetAsync(rowCur, 0, (size_t)NN * 4, stream);
  hipMemsetAsync(colCur, 0, (size_t)NN * 4, stream);

  transpose_k<<<(512 * 256 + 255) / 256, 256, 0, stream>>>(W1l, W1lrT, 512, 256);
  transpose_k<<<(512 * 256 + 255) / 256, 256, 0, stream>>>(W1r, W1lrT + (size_t)256 * 512, 512, 256);
  transpose_k<<<(ED * 256 + 255) / 256, 256, 0, stream>>>(W1e, BtE, ED, 256);
  transpose_k<<<(ED * 64 + 255) / 256, 256, 0, stream>>>(W2e, BtE + (size_t)256 * ED, ED, 64);
  transpose_k<<<(256 * 64 + 255) / 256, 256, 0, stream>>>(W2l, W2lrT, 256, 64);
  transpose_k<<<(256 * 64 + 255) / 256, 256, 0, stream>>>(W2r, W2lrT + (size_t)64 * 256, 256, 64);
  concatbias_k<<<3, 256, 0, stream>>>(b1l, b1r, b2l, b2r, biasLR1, biasLR2);

  hist_k<<<(NE + 255) / 256, 256, 0, stream>>>(rowA, colA, degR, degC);
  scan_k<<<1, 256, 0, stream>>>(degR, degC, rowPtr, colPtr);
  scatter_k<<<(NE + 255) / 256, 256, 0, stream>>>(rowA, colA, rowPtr, colPtr,
                                                  rowCur, colCur, rowIdx, colIdx);
  loopattr_k<<<(NN + 3) / 4, 256, 0, stream>>>(colPtr, colIdx, eattr, loopA16);

  // XLR1 = x @ [W1l|W1r] + [b1l|b1r]  -> [NN, 512] bf16
  dim3 gx1((NN + 127) / 128, 8);
  gemm_k<<<gx1, 256, 0, stream>>>(x, 1, W1lrT, NN, 512, 512, biasLR1, XLR1);
  // fused edge GEMM: logit1 + ep2
  edge_k<<<(ETOT + 63) / 64, 256, 0, stream>>>(eattr, loopA16, BtE, rowA, colA,
                                               XLR1, att1, logit1, ep2);
  agg1_k<<<(NN + 3) / 4, 256, 0, stream>>>(rowPtr, rowIdx, (const float4*)logit1,
                                           XLR1, 512, colA, bias1, H1);
  // XLR2 = H1 @ [W2l|W2r] + [b2l|b2r]  -> [NN, 128] bf16
  dim3 gx2((NN + 127) / 128, 2);
  gemm_k<<<gx2, 256, 0, stream>>>(H1, 0, W2lrT, NN, 256, 128, biasLR2, XLR2);
  logit2_k<<<(ETOT + 15) / 16, 256, 0, stream>>>(rowA, colA, ep2, XLR2, att2, logit2);
  agg2_k<<<(NN + 3) / 4, 256, 0, stream>>>(rowPtr, rowIdx, logit2, XLR2, 128, colA, bias2, H2);

  float* outCls = (float*)d_out;
  float* outGn  = outCls + (size_t)NG * NCLS;
  poolln_k<<<NG, 256, 0, stream>>>(H2, lng, lnb, outGn);
  clf_k<<<NG, 256, 0, stream>>>(outGn, clfW, clfb, outCls);
}

// Round 2
// 1025.552 us; speedup vs baseline: 1.1189x; 1.1189x over previous
//
#include <hip/hip_runtime.h>

#define NN 20000      // nodes
#define NE 200000     // edges
#define NH1 256       // H*C layer1
#define ED 384
#define NG 64
#define NCLS 751
#define ETOT (NE + NN)   // 220000 edges incl self loops

typedef unsigned short u16;
typedef __attribute__((ext_vector_type(8))) short short8;
typedef __attribute__((ext_vector_type(4))) float f32x4;

__device__ __forceinline__ float bf2f(u16 u){
  union { unsigned int i; float f; } v; v.i = ((unsigned int)u) << 16; return v.f;
}
__device__ __forceinline__ u16 f2bf(float f){
  union { float f; unsigned int i; } v; v.f = f;
  return (u16)((v.i + 0x7fffu + ((v.i >> 16) & 1u)) >> 16);
}

// ---------- prep kernels ----------
// transpose + f32->bf16: in [K,N] f32 row-major -> out [N,K] bf16
__global__ void transpose_k(const float* __restrict__ in, u16* __restrict__ out, int K, int N){
  int idx = blockIdx.x * 256 + threadIdx.x;
  if (idx >= K * N) return;
  int k = idx / N, n = idx - k * N;
  out[n * K + k] = f2bf(in[idx]);
}

__global__ void concatbias_k(const float* __restrict__ b1l, const float* __restrict__ b1r,
                             const float* __restrict__ b2l, const float* __restrict__ b2r,
                             float* __restrict__ biasLR1, float* __restrict__ biasLR2){
  int i = blockIdx.x * 256 + threadIdx.x;
  if (i < 256) biasLR1[i] = b1l[i];
  else if (i < 512) biasLR1[i] = b1r[i - 256];
  else if (i < 576) biasLR2[i - 512] = b2l[i - 512];
  else if (i < 640) biasLR2[i - 512] = b2r[i - 576];
}

__global__ void hist_k(const int* __restrict__ rowA, const int* __restrict__ colA,
                       int* __restrict__ degR, int* __restrict__ degC){
  int e = blockIdx.x * 256 + threadIdx.x;
  if (e >= NE) return;
  atomicAdd(&degR[rowA[e]], 1);
  atomicAdd(&degC[colA[e]], 1);
}

__global__ void scan_k(const int* __restrict__ degR, const int* __restrict__ degC,
                       int* __restrict__ rowPtr, int* __restrict__ colPtr){
  __shared__ int sR[256], sC[256];
  int t = threadIdx.x;
  const int chunk = (NN + 255) / 256;
  int beg = t * chunk, end = min(beg + chunk, NN);
  int aR = 0, aC = 0;
  for (int i = beg; i < end; i++){ aR += degR[i]; aC += degC[i]; }
  sR[t] = aR; sC[t] = aC;
  __syncthreads();
  for (int off = 1; off < 256; off <<= 1){
    int vR = 0, vC = 0;
    if (t >= off){ vR = sR[t - off]; vC = sC[t - off]; }
    __syncthreads();
    sR[t] += vR; sC[t] += vC;
    __syncthreads();
  }
  int rR = (t == 0) ? 0 : sR[t - 1];
  int rC = (t == 0) ? 0 : sC[t - 1];
  for (int i = beg; i < end; i++){
    rowPtr[i] = rR; rR += degR[i];
    colPtr[i] = rC; rC += degC[i];
  }
  if (t == 255){ rowPtr[NN] = sR[255]; colPtr[NN] = sC[255]; }
}

__global__ void scatter_k(const int* __restrict__ rowA, const int* __restrict__ colA,
                          const int* __restrict__ rowPtr, const int* __restrict__ colPtr,
                          int* __restrict__ rowCur, int* __restrict__ colCur,
                          int* __restrict__ rowIdx, int* __restrict__ colIdx){
  int e = blockIdx.x * 256 + threadIdx.x;
  if (e >= NE) return;
  int r = rowA[e]; int p = atomicAdd(&rowCur[r], 1); rowIdx[rowPtr[r] + p] = e;
  int c = colA[e]; int q = atomicAdd(&colCur[c], 1); colIdx[colPtr[c] + q] = e;
}

// loop_attr[n] = mean over incoming (col) edges of edge_attr -> bf16
__global__ __launch_bounds__(256) void loopattr_k(const int* __restrict__ colPtr,
                                                  const int* __restrict__ colIdx,
                                                  const float* __restrict__ eattr,
                                                  u16* __restrict__ loopA16){
  int node = blockIdx.x * 4 + (threadIdx.x >> 6);
  if (node >= NN) return;
  int lane = threadIdx.x & 63;
  int p0 = colPtr[node], deg = colPtr[node + 1] - p0;
  float inv = 1.f / fmaxf((float)deg, 1.f);
  float s[6] = {0.f, 0.f, 0.f, 0.f, 0.f, 0.f};
  for (int t = 0; t < deg; t++){
    const float* rowp = eattr + (size_t)colIdx[p0 + t] * ED;
    #pragma unroll
    for (int c0 = 0; c0 < 6; c0++) s[c0] += rowp[c0 * 64 + lane];
  }
  u16* outp = loopA16 + (size_t)node * ED;
  #pragma unroll
  for (int c0 = 0; c0 < 6; c0++) outp[c0 * 64 + lane] = f2bf(s[c0] * inv);
}

// ---------- generic node GEMM (mode-0 only): C[M,Ntot] = A[M,K] x B, bf16 out + f32 bias
__global__ __launch_bounds__(256)
void gemm_k(const void* __restrict__ Av, int aF32,
            const u16* __restrict__ Bt, int M, int K, int Ntot,
            const float* __restrict__ bias, u16* __restrict__ outBf)
{
  __shared__ __align__(16) u16 lA[128 * 40];
  __shared__ __align__(16) u16 lB[64 * 40];
  const int tid  = threadIdx.x;
  const int lane = tid & 63;
  const int wave = tid >> 6;
  const int m0 = blockIdx.x * 128;
  const int n0 = blockIdx.y * 64;
  const int lr  = tid >> 2;
  const int lkc = (tid & 3) << 3;
  const int lm = lane & 15;
  const int lk = (lane >> 4) << 3;
  const int wrow = wave << 5;

  f32x4 acc[2][4];
  #pragma unroll
  for (int i = 0; i < 2; i++)
    #pragma unroll
    for (int j = 0; j < 4; j++) acc[i][j] = (f32x4){0.f, 0.f, 0.f, 0.f};

  for (int k0 = 0; k0 < K; k0 += 32){
    #pragma unroll
    for (int p = 0; p < 2; p++){
      int row = lr + (p << 6);
      int gm = m0 + row;
      union { u16 h[8]; uint4 v; } pk;
      pk.v = make_uint4(0u, 0u, 0u, 0u);
      if (gm < M){
        if (aF32){
          const float* src = (const float*)Av + (size_t)gm * K + k0 + lkc;
          float4 f0 = *(const float4*)src;
          float4 f1 = *(const float4*)(src + 4);
          pk.h[0] = f2bf(f0.x); pk.h[1] = f2bf(f0.y); pk.h[2] = f2bf(f0.z); pk.h[3] = f2bf(f0.w);
          pk.h[4] = f2bf(f1.x); pk.h[5] = f2bf(f1.y); pk.h[6] = f2bf(f1.z); pk.h[7] = f2bf(f1.w);
        } else {
          pk.v = *(const uint4*)((const u16*)Av + (size_t)gm * K + k0 + lkc);
        }
      }
      *(uint4*)(&lA[row * 40 + lkc]) = pk.v;
    }
    *(uint4*)(&lB[lr * 40 + lkc]) = *(const uint4*)(Bt + (size_t)(n0 + lr) * K + k0 + lkc);
    __syncthreads();
    short8 a0 = *(const short8*)(&lA[(wrow + lm) * 40 + lk]);
    short8 a1 = *(const short8*)(&lA[(wrow + 16 + lm) * 40 + lk]);
    #pragma unroll
    for (int nj = 0; nj < 4; nj++){
      short8 b = *(const short8*)(&lB[(nj * 16 + lm) * 40 + lk]);
      acc[0][nj] = __builtin_amdgcn_mfma_f32_16x16x32_bf16(a0, b, acc[0][nj], 0, 0, 0);
      acc[1][nj] = __builtin_amdgcn_mfma_f32_16x16x32_bf16(a1, b, acc[1][nj], 0, 0, 0);
    }
    __syncthreads();
  }

  #pragma unroll
  for (int mi = 0; mi < 2; mi++)
    #pragma unroll
    for (int r4 = 0; r4 < 4; r4++){
      int row = wrow + mi * 16 + ((lane >> 4) << 2) + r4;
      int gm = m0 + row;
      if (gm < M){
        #pragma unroll
        for (int nj = 0; nj < 4; nj++){
          int gc = n0 + nj * 16 + lm;
          outBf[(size_t)gm * Ntot + gc] = f2bf(acc[mi][nj][r4] + bias[gc]);
        }
      }
    }
}

// ---------- fused edge GEMM: ea[ETOT,384] x [W1e|W2e][384,320] ----------
// 128-row tile, 8 waves (512 thr): wave = (rowhalf<<2)|head. Per-wave work identical
// to the 64-row version (acc[4][5], 20 MFMA/iter) -> same VGPR, but half the blocks
// (half the latency-drain events, half the B L2 re-reads) and 24 waves/CU TLP.
__global__ __launch_bounds__(512)
void edge_k(const float* __restrict__ eattr, const u16* __restrict__ loopA16,
            const u16* __restrict__ BtE,     // [320 x 384] bf16
            const int* __restrict__ rowA, const int* __restrict__ colA,
            const u16* __restrict__ XLR1,    // [NN x 512] bf16 = [xl1 | xr1]
            const float* __restrict__ att1,  // [256] f32
            float* __restrict__ logit1,      // [ETOT x 4] f32
            u16* __restrict__ ep2)           // [ETOT x 64] bf16
{
  __shared__ __align__(16) u16 lA[128 * 40];
  __shared__ __align__(16) u16 lB[320 * 40];
  const int tid = threadIdx.x;
  const int lane = tid & 63;
  const int wave = tid >> 6;            // 0..7
  const int head = wave & 3;            // 0..3
  const int wrow = (wave >> 2) << 6;    // 0 or 64
  const int m0 = blockIdx.x * 128;
  const int lm = lane & 15;
  const int lk = (lane >> 4) << 3;
  const int arow = tid >> 2;            // 0..127
  const int akc = (tid & 3) << 3;       // 0,8,16,24

  f32x4 acc[4][5];
  #pragma unroll
  for (int i = 0; i < 4; i++)
    #pragma unroll
    for (int j = 0; j < 5; j++) acc[i][j] = (f32x4){0.f, 0.f, 0.f, 0.f};

  const int gmA = m0 + arow;

  for (int k0 = 0; k0 < ED; k0 += 32){
    {
      union { u16 h[8]; uint4 v; } pk;
      pk.v = make_uint4(0u, 0u, 0u, 0u);
      if (gmA < ETOT){
        if (gmA < NE){
          const float* src = eattr + (size_t)gmA * ED + k0 + akc;
          float4 f0 = *(const float4*)src;
          float4 f1 = *(const float4*)(src + 4);
          pk.h[0] = f2bf(f0.x); pk.h[1] = f2bf(f0.y); pk.h[2] = f2bf(f0.z); pk.h[3] = f2bf(f0.w);
          pk.h[4] = f2bf(f1.x); pk.h[5] = f2bf(f1.y); pk.h[6] = f2bf(f1.z); pk.h[7] = f2bf(f1.w);
        } else {
          pk.v = *(const uint4*)(loopA16 + (size_t)(gmA - NE) * ED + k0 + akc);
        }
      }
      *(uint4*)(&lA[arow * 40 + akc]) = pk.v;
    }
    #pragma unroll
    for (int s = 0; s < 2; s++){
      int r = (tid >> 2) + s * 128;
      *(uint4*)(&lB[r * 40 + akc]) = *(const uint4*)(BtE + (size_t)r * ED + k0 + akc);
    }
    if (tid < 256){
      int r = 256 + (tid >> 2);
      *(uint4*)(&lB[r * 40 + akc]) = *(const uint4*)(BtE + (size_t)r * ED + k0 + akc);
    }
    __syncthreads();
    short8 a[4];
    #pragma unroll
    for (int mi = 0; mi < 4; mi++) a[mi] = *(const short8*)(&lA[(wrow + mi * 16 + lm) * 40 + lk]);
    #pragma unroll
    for (int nj = 0; nj < 4; nj++){
      short8 b = *(const short8*)(&lB[(head * 64 + nj * 16 + lm) * 40 + lk]);
      #pragma unroll
      for (int mi = 0; mi < 4; mi++)
        acc[mi][nj] = __builtin_amdgcn_mfma_f32_16x16x32_bf16(a[mi], b, acc[mi][nj], 0, 0, 0);
    }
    {
      short8 b = *(const short8*)(&lB[(256 + head * 16 + lm) * 40 + lk]);
      #pragma unroll
      for (int mi = 0; mi < 4; mi++)
        acc[mi][4] = __builtin_amdgcn_mfma_f32_16x16x32_bf16(a[mi], b, acc[mi][4], 0, 0, 0);
    }
    __syncthreads();
  }

  float attc[4];
  #pragma unroll
  for (int nj = 0; nj < 4; nj++) attc[nj] = att1[head * 64 + nj * 16 + lm];
  const int quad4 = (lane >> 4) << 2;
  #pragma unroll
  for (int mi = 0; mi < 4; mi++)
    #pragma unroll
    for (int r4 = 0; r4 < 4; r4++){
      int e = m0 + wrow + mi * 16 + quad4 + r4;
      float partial = 0.f;
      if (e < ETOT){
        int ii = (e < NE) ? rowA[e] : (e - NE);
        int jj = (e < NE) ? colA[e] : (e - NE);
        const u16* xlp = XLR1 + (size_t)jj * 512 + head * 64;
        const u16* xrp = XLR1 + (size_t)ii * 512 + 256 + head * 64;
        #pragma unroll
        for (int nj = 0; nj < 4; nj++){
          float v = acc[mi][nj][r4] + bf2f(xlp[nj * 16 + lm]) + bf2f(xrp[nj * 16 + lm]);
          v = (v > 0.f) ? v : 0.2f * v;
          partial += v * attc[nj];
        }
        ep2[(size_t)e * 64 + head * 16 + lm] = f2bf(acc[mi][4][r4]);
      }
      partial += __shfl_xor(partial, 1);
      partial += __shfl_xor(partial, 2);
      partial += __shfl_xor(partial, 4);
      partial += __shfl_xor(partial, 8);
      if (lm == 0 && e < ETOT) logit1[(size_t)e * 4 + head] = partial;
    }
}

// ---------- layer-2 logit epilogue: logit2[e] = sum_c att2[c]*leaky0.2(ep2+xl2[j]+xr2[i])
__global__ __launch_bounds__(256) void logit2_k(const int* __restrict__ rowA,
    const int* __restrict__ colA, const u16* __restrict__ ep2,
    const u16* __restrict__ XLR2,   // [NN x 128] = [xl2 | xr2]
    const float* __restrict__ att2, float* __restrict__ logit2)
{
  int e = blockIdx.x * 16 + (threadIdx.x >> 4);
  if (e >= ETOT) return;
  int lm = threadIdx.x & 15;
  int ii = (e < NE) ? rowA[e] : (e - NE);
  int jj = (e < NE) ? colA[e] : (e - NE);
  ushort4 pe = *(const ushort4*)(ep2 + (size_t)e * 64 + lm * 4);
  ushort4 pl = *(const ushort4*)(XLR2 + (size_t)jj * 128 + lm * 4);
  ushort4 pr = *(const ushort4*)(XLR2 + (size_t)ii * 128 + 64 + lm * 4);
  float s = 0.f;
  float v0 = bf2f(pe.x) + bf2f(pl.x) + bf2f(pr.x); v0 = v0 > 0.f ? v0 : 0.2f * v0;
  float v1 = bf2f(pe.y) + bf2f(pl.y) + bf2f(pr.y); v1 = v1 > 0.f ? v1 : 0.2f * v1;
  float v2 = bf2f(pe.z) + bf2f(pl.z) + bf2f(pr.z); v2 = v2 > 0.f ? v2 : 0.2f * v2;
  float v3 = bf2f(pe.w) + bf2f(pl.w) + bf2f(pr.w); v3 = v3 > 0.f ? v3 : 0.2f * v3;
  s = v0 * att2[lm * 4] + v1 * att2[lm * 4 + 1] + v2 * att2[lm * 4 + 2] + v3 * att2[lm * 4 + 3];
  s += __shfl_xor(s, 1);
  s += __shfl_xor(s, 2);
  s += __shfl_xor(s, 4);
  s += __shfl_xor(s, 8);
  if (lm == 0) logit2[e] = s;
}

// ---------- segment softmax + aggregation, layer 1 (H=4, C=64) ----------
__global__ __launch_bounds__(256) void agg1_k(const int* __restrict__ rowPtr,
    const int* __restrict__ rowIdx, const float4* __restrict__ lg4,
    const u16* __restrict__ XL1, int xstride, const int* __restrict__ colA,
    const float* __restrict__ bias1, u16* __restrict__ H1)
{
  int node = blockIdx.x * 4 + (threadIdx.x >> 6);
  if (node >= NN) return;
  int lane = threadIdx.x & 63;
  int p0 = rowPtr[node], deg = rowPtr[node + 1] - p0;
  float4 sl = lg4[NE + node];
  float m0 = sl.x, m1 = sl.y, m2 = sl.z, m3 = sl.w;
  for (int t = lane; t < deg; t += 64){
    float4 l = lg4[rowIdx[p0 + t]];
    m0 = fmaxf(m0, l.x); m1 = fmaxf(m1, l.y); m2 = fmaxf(m2, l.z); m3 = fmaxf(m3, l.w);
  }
  #pragma unroll
  for (int off = 32; off > 0; off >>= 1){
    m0 = fmaxf(m0, __shfl_xor(m0, off));
    m1 = fmaxf(m1, __shfl_xor(m1, off));
    m2 = fmaxf(m2, __shfl_xor(m2, off));
    m3 = fmaxf(m3, __shfl_xor(m3, off));
  }
  float d0, d1, d2, d3, a0, a1, a2, a3;
  {
    float e0 = __expf(sl.x - m0), e1 = __expf(sl.y - m1), e2 = __expf(sl.z - m2), e3 = __expf(sl.w - m3);
    d0 = e0; d1 = e1; d2 = e2; d3 = e3;
    const u16* xp = XL1 + (size_t)node * xstride;
    a0 = e0 * bf2f(xp[lane]); a1 = e1 * bf2f(xp[64 + lane]);
    a2 = e2 * bf2f(xp[128 + lane]); a3 = e3 * bf2f(xp[192 + lane]);
  }
  for (int t = 0; t < deg; t++){
    int e = rowIdx[p0 + t];
    float4 l = lg4[e];
    int j = colA[e];
    float e0 = __expf(l.x - m0), e1 = __expf(l.y - m1), e2 = __expf(l.z - m2), e3 = __expf(l.w - m3);
    d0 += e0; d1 += e1; d2 += e2; d3 += e3;
    const u16* xp = XL1 + (size_t)j * xstride;
    a0 += e0 * bf2f(xp[lane]); a1 += e1 * bf2f(xp[64 + lane]);
    a2 += e2 * bf2f(xp[128 + lane]); a3 += e3 * bf2f(xp[192 + lane]);
  }
  float v0 = a0 / d0 + bias1[lane];
  float v1 = a1 / d1 + bias1[64 + lane];
  float v2 = a2 / d2 + bias1[128 + lane];
  float v3 = a3 / d3 + bias1[192 + lane];
  v0 = v0 > 0.f ? v0 : 0.01f * v0;
  v1 = v1 > 0.f ? v1 : 0.01f * v1;
  v2 = v2 > 0.f ? v2 : 0.01f * v2;
  v3 = v3 > 0.f ? v3 : 0.01f * v3;
  u16* hp = H1 + (size_t)node * NH1;
  hp[lane] = f2bf(v0); hp[64 + lane] = f2bf(v1);
  hp[128 + lane] = f2bf(v2); hp[192 + lane] = f2bf(v3);
}

// ---------- layer 2 softmax+agg (H=1, C=64) ----------
__global__ __launch_bounds__(256) void agg2_k(const int* __restrict__ rowPtr,
    const int* __restrict__ rowIdx, const float* __restrict__ lg,
    const u16* __restrict__ XL2, int xstride, const int* __restrict__ colA,
    const float* __restrict__ bias2, float* __restrict__ H2)
{
  int node = blockIdx.x * 4 + (threadIdx.x >> 6);
  if (node >= NN) return;
  int lane = threadIdx.x & 63;
  int p0 = rowPtr[node], deg = rowPtr[node + 1] - p0;
  float sl = lg[NE + node];
  float mx = sl;
  for (int t = lane; t < deg; t += 64) mx = fmaxf(mx, lg[rowIdx[p0 + t]]);
  #pragma unroll
  for (int off = 32; off > 0; off >>= 1) mx = fmaxf(mx, __shfl_xor(mx, off));
  float den = __expf(sl - mx);
  float acc = den * bf2f(XL2[(size_t)node * xstride + lane]);
  for (int t = 0; t < deg; t++){
    int e = rowIdx[p0 + t];
    float ex = __expf(lg[e] - mx);
    den += ex;
    acc += ex * bf2f(XL2[(size_t)colA[e] * xstride + lane]);
  }
  float v = acc / den + bias2[lane];
  v = v > 0.f ? v : 0.01f * v;
  H2[(size_t)node * 64 + lane] = v;
}

// ---------- global max pool + LayerNorm (C=64), 4 waves/block ----------
__global__ __launch_bounds__(256) void poolln_k(const float* __restrict__ H2,
    const float* __restrict__ lng, const float* __restrict__ lnb, float* __restrict__ outGn)
{
  __shared__ float sm[4][64];
  int g = blockIdx.x, w = threadIdx.x >> 6, c = threadIdx.x & 63;
  int beg = (g * NN + NG - 1) / NG;
  int end = ((g + 1) * NN + NG - 1) / NG;
  float m = -3.0e38f;
  for (int n = beg + w; n < end; n += 4) m = fmaxf(m, H2[(size_t)n * 64 + c]);
  sm[w][c] = m;
  __syncthreads();
  if (threadIdx.x < 64){
    m = fmaxf(fmaxf(sm[0][c], sm[1][c]), fmaxf(sm[2][c], sm[3][c]));
    float s = m;
    #pragma unroll
    for (int off = 32; off > 0; off >>= 1) s += __shfl_xor(s, off);
    float mu = s * (1.f / 64.f);
    float d = m - mu;
    float vv = d * d;
    #pragma unroll
    for (int off = 32; off > 0; off >>= 1) vv += __shfl_xor(vv, off);
    float var = vv * (1.f / 64.f);
    outGn[g * 64 + c] = d * rsqrtf(var + 1e-5f) * lng[c] + lnb[c];
  }
}

// ---------- classifier [G,64] @ [64,751] + b ----------
__global__ __launch_bounds__(256) void clf_k(const float* __restrict__ gn,
    const float* __restrict__ W, const float* __restrict__ b, float* __restrict__ outCls)
{
  __shared__ float sg[64];
  int g = blockIdx.x;
  if (threadIdx.x < 64) sg[threadIdx.x] = gn[g * 64 + threadIdx.x];
  __syncthreads();
  for (int o = threadIdx.x; o < NCLS; o += 256){
    float s = b[o];
    #pragma unroll 16
    for (int c = 0; c < 64; c++) s += sg[c] * W[c * NCLS + o];
    outCls[(size_t)g * NCLS + o] = s;
  }
}

extern "C" void kernel_launch(void* const* d_in, const int* in_sizes, int n_in,
                              void* d_out, int out_size, void* d_ws, size_t ws_size,
                              hipStream_t stream)
{
  const float* x     = (const float*)d_in[0];
  const int*   eidx  = (const int*)d_in[1];
  const float* eattr = (const float*)d_in[2];
  const float* W1l = (const float*)d_in[4];
  const float* b1l = (const float*)d_in[5];
  const float* W1r = (const float*)d_in[6];
  const float* b1r = (const float*)d_in[7];
  const float* W1e = (const float*)d_in[8];
  const float* att1 = (const float*)d_in[9];
  const float* bias1 = (const float*)d_in[10];
  const float* W2l = (const float*)d_in[11];
  const float* b2l = (const float*)d_in[12];
  const float* W2r = (const float*)d_in[13];
  const float* b2r = (const float*)d_in[14];
  const float* W2e = (const float*)d_in[15];
  const float* att2 = (const float*)d_in[16];
  const float* bias2 = (const float*)d_in[17];
  const float* lng = (const float*)d_in[18];
  const float* lnb = (const float*)d_in[19];
  const float* clfW = (const float*)d_in[20];
  const float* clfb = (const float*)d_in[21];
  const int* rowA = eidx;        // ei_i (aggregation target)
  const int* colA = eidx + NE;   // ei_j (message source)

  char* w = (char*)d_ws;
  auto alloc = [&](size_t b) -> char* {
    char* p = w; w += (b + 255) & ~(size_t)255; return p;
  };
  u16* W1lrT  = (u16*)alloc((size_t)512 * 512 * 2);   // [512 cols x 512 K]
  u16* BtE    = (u16*)alloc((size_t)320 * ED * 2);    // [W1e|W2e]^T
  u16* W2lrT  = (u16*)alloc((size_t)128 * 256 * 2);
  float* biasLR1 = (float*)alloc(512 * 4);
  float* biasLR2 = (float*)alloc(128 * 4);
  int* degR   = (int*)alloc((size_t)NN * 4);
  int* degC   = (int*)alloc((size_t)NN * 4);
  int* rowPtr = (int*)alloc((size_t)(NN + 1) * 4);
  int* colPtr = (int*)alloc((size_t)(NN + 1) * 4);
  int* rowCur = (int*)alloc((size_t)NN * 4);
  int* colCur = (int*)alloc((size_t)NN * 4);
  int* rowIdx = (int*)alloc((size_t)NE * 4);
  int* colIdx = (int*)alloc((size_t)NE * 4);
  char* loopRegion = alloc((size_t)NN * ED * 2);      // 15.36 MB, reused after edge_k
  u16* loopA16 = (u16*)loopRegion;
  u16* XLR1   = (u16*)alloc((size_t)NN * 512 * 2);
  float* logit1 = (float*)alloc((size_t)ETOT * 4 * 4);
  u16* H1     = (u16*)alloc((size_t)NN * NH1 * 2);
  u16* ep2    = (u16*)alloc((size_t)ETOT * 64 * 2);
  // aliased into loopRegion (loopA16's last reader is edge_k):
  u16* XLR2   = (u16*)loopRegion;                               // 5.12 MB
  float* logit2 = (float*)(loopRegion + (size_t)5500928);       // 0.88 MB
  float* H2   = (float*)(loopRegion + (size_t)6553600);         // 5.12 MB

  hipMemsetAsync(degR, 0, (size_t)NN * 4, stream);
  hipMemsetAsync(degC, 0, (size_t)NN * 4, stream);
  hipMemsetAsync(rowCur, 0, (size_t)NN * 4, stream);
  hipMemsetAsync(colCur, 0, (size_t)NN * 4, stream);

  transpose_k<<<(512 * 256 + 255) / 256, 256, 0, stream>>>(W1l, W1lrT, 512, 256);
  transpose_k<<<(512 * 256 + 255) / 256, 256, 0, stream>>>(W1r, W1lrT + (size_t)256 * 512, 512, 256);
  transpose_k<<<(ED * 256 + 255) / 256, 256, 0, stream>>>(W1e, BtE, ED, 256);
  transpose_k<<<(ED * 64 + 255) / 256, 256, 0, stream>>>(W2e, BtE + (size_t)256 * ED, ED, 64);
  transpose_k<<<(256 * 64 + 255) / 256, 256, 0, stream>>>(W2l, W2lrT, 256, 64);
  transpose_k<<<(256 * 64 + 255) / 256, 256, 0, stream>>>(W2r, W2lrT + (size_t)64 * 256, 256, 64);
  concatbias_k<<<3, 256, 0, stream>>>(b1l, b1r, b2l, b2r, biasLR1, biasLR2);

  hist_k<<<(NE + 255) / 256, 256, 0, stream>>>(rowA, colA, degR, degC);
  scan_k<<<1, 256, 0, stream>>>(degR, degC, rowPtr, colPtr);
  scatter_k<<<(NE + 255) / 256, 256, 0, stream>>>(rowA, colA, rowPtr, colPtr,
                                                  rowCur, colCur, rowIdx, colIdx);
  loopattr_k<<<(NN + 3) / 4, 256, 0, stream>>>(colPtr, colIdx, eattr, loopA16);

  // XLR1 = x @ [W1l|W1r] + [b1l|b1r]  -> [NN, 512] bf16
  dim3 gx1((NN + 127) / 128, 8);
  gemm_k<<<gx1, 256, 0, stream>>>(x, 1, W1lrT, NN, 512, 512, biasLR1, XLR1);
  // fused edge GEMM: logit1 + ep2
  edge_k<<<(ETOT + 127) / 128, 512, 0, stream>>>(eattr, loopA16, BtE, rowA, colA,
                                                 XLR1, att1, logit1, ep2);
  agg1_k<<<(NN + 3) / 4, 256, 0, stream>>>(rowPtr, rowIdx, (const float4*)logit1,
                                           XLR1, 512, colA, bias1, H1);
  // XLR2 = H1 @ [W2l|W2r] + [b2l|b2r]  -> [NN, 128] bf16
  dim3 gx2((NN + 127) / 128, 2);
  gemm_k<<<gx2, 256, 0, stream>>>(H1, 0, W2lrT, NN, 256, 128, biasLR2, XLR2);
  logit2_k<<<(ETOT + 15) / 16, 256, 0, stream>>>(rowA, colA, ep2, XLR2, att2, logit2);
  agg2_k<<<(NN + 3) / 4, 256, 0, stream>>>(rowPtr, rowIdx, logit2, XLR2, 128, colA, bias2, H2);

  float* outCls = (float*)d_out;
  float* outGn  = outCls + (size_t)NG * NCLS;
  poolln_k<<<NG, 256, 0, stream>>>(H2, lng, lnb, outGn);
  clf_k<<<NG, 256, 0, stream>>>(outGn, clfW, clfb, outCls);
}

// Round 3
// 967.099 us; speedup vs baseline: 1.1865x; 1.0604x over previous
//
#include <hip/hip_runtime.h>

#define NN 20000      // nodes
#define NE 200000     // edges
#define NH1 256       // H*C layer1
#define ED 384
#define NG 64
#define NCLS 751
#define ETOT (NE + NN)   // 220000 edges incl self loops

typedef unsigned short u16;
typedef __attribute__((ext_vector_type(8))) short short8;
typedef __attribute__((ext_vector_type(4))) float f32x4;

__device__ __forceinline__ float bf2f(u16 u){
  union { unsigned int i; float f; } v; v.i = ((unsigned int)u) << 16; return v.f;
}
__device__ __forceinline__ u16 f2bf(float f){
  union { float f; unsigned int i; } v; v.f = f;
  return (u16)((v.i + 0x7fffu + ((v.i >> 16) & 1u)) >> 16);
}

// ---------- prep kernels ----------
// transpose + f32->bf16: in [K,N] f32 row-major -> out [N,K] bf16
__global__ void transpose_k(const float* __restrict__ in, u16* __restrict__ out, int K, int N){
  int idx = blockIdx.x * 256 + threadIdx.x;
  if (idx >= K * N) return;
  int k = idx / N, n = idx - k * N;
  out[n * K + k] = f2bf(in[idx]);
}

__global__ void concatbias_k(const float* __restrict__ b1l, const float* __restrict__ b1r,
                             const float* __restrict__ b2l, const float* __restrict__ b2r,
                             float* __restrict__ biasLR1, float* __restrict__ biasLR2){
  int i = blockIdx.x * 256 + threadIdx.x;
  if (i < 256) biasLR1[i] = b1l[i];
  else if (i < 512) biasLR1[i] = b1r[i - 256];
  else if (i < 576) biasLR2[i - 512] = b2l[i - 512];
  else if (i < 640) biasLR2[i - 512] = b2r[i - 576];
}

__global__ void hist_k(const int* __restrict__ rowA, const int* __restrict__ colA,
                       int* __restrict__ degR, int* __restrict__ degC){
  int e = blockIdx.x * 256 + threadIdx.x;
  if (e >= NE) return;
  atomicAdd(&degR[rowA[e]], 1);
  atomicAdd(&degC[colA[e]], 1);
}

__global__ void scan_k(const int* __restrict__ degR, const int* __restrict__ degC,
                       int* __restrict__ rowPtr, int* __restrict__ colPtr){
  __shared__ int sR[256], sC[256];
  int t = threadIdx.x;
  const int chunk = (NN + 255) / 256;
  int beg = t * chunk, end = min(beg + chunk, NN);
  int aR = 0, aC = 0;
  for (int i = beg; i < end; i++){ aR += degR[i]; aC += degC[i]; }
  sR[t] = aR; sC[t] = aC;
  __syncthreads();
  for (int off = 1; off < 256; off <<= 1){
    int vR = 0, vC = 0;
    if (t >= off){ vR = sR[t - off]; vC = sC[t - off]; }
    __syncthreads();
    sR[t] += vR; sC[t] += vC;
    __syncthreads();
  }
  int rR = (t == 0) ? 0 : sR[t - 1];
  int rC = (t == 0) ? 0 : sC[t - 1];
  for (int i = beg; i < end; i++){
    rowPtr[i] = rR; rR += degR[i];
    colPtr[i] = rC; rC += degC[i];
  }
  if (t == 255){ rowPtr[NN] = sR[255]; colPtr[NN] = sC[255]; }
}

__global__ void scatter_k(const int* __restrict__ rowA, const int* __restrict__ colA,
                          const int* __restrict__ rowPtr, const int* __restrict__ colPtr,
                          int* __restrict__ rowCur, int* __restrict__ colCur,
                          int* __restrict__ rowIdx, int* __restrict__ colIdx){
  int e = blockIdx.x * 256 + threadIdx.x;
  if (e >= NE) return;
  int r = rowA[e]; int p = atomicAdd(&rowCur[r], 1); rowIdx[rowPtr[r] + p] = e;
  int c = colA[e]; int q = atomicAdd(&colCur[c], 1); colIdx[colPtr[c] + q] = e;
}

// loop_attr[n] = mean over incoming (col) edges of edge_attr -> bf16
__global__ __launch_bounds__(256) void loopattr_k(const int* __restrict__ colPtr,
                                                  const int* __restrict__ colIdx,
                                                  const float* __restrict__ eattr,
                                                  u16* __restrict__ loopA16){
  int node = blockIdx.x * 4 + (threadIdx.x >> 6);
  if (node >= NN) return;
  int lane = threadIdx.x & 63;
  int p0 = colPtr[node], deg = colPtr[node + 1] - p0;
  float inv = 1.f / fmaxf((float)deg, 1.f);
  float s[6] = {0.f, 0.f, 0.f, 0.f, 0.f, 0.f};
  for (int t = 0; t < deg; t++){
    const float* rowp = eattr + (size_t)colIdx[p0 + t] * ED;
    #pragma unroll
    for (int c0 = 0; c0 < 6; c0++) s[c0] += rowp[c0 * 64 + lane];
  }
  u16* outp = loopA16 + (size_t)node * ED;
  #pragma unroll
  for (int c0 = 0; c0 < 6; c0++) outp[c0 * 64 + lane] = f2bf(s[c0] * inv);
}

// ---------- generic node GEMM (mode-0 only): C[M,Ntot] = A[M,K] x B, bf16 out + f32 bias
__global__ __launch_bounds__(256)
void gemm_k(const void* __restrict__ Av, int aF32,
            const u16* __restrict__ Bt, int M, int K, int Ntot,
            const float* __restrict__ bias, u16* __restrict__ outBf)
{
  __shared__ __align__(16) u16 lA[128 * 40];
  __shared__ __align__(16) u16 lB[64 * 40];
  const int tid  = threadIdx.x;
  const int lane = tid & 63;
  const int wave = tid >> 6;
  const int m0 = blockIdx.x * 128;
  const int n0 = blockIdx.y * 64;
  const int lr  = tid >> 2;
  const int lkc = (tid & 3) << 3;
  const int lm = lane & 15;
  const int lk = (lane >> 4) << 3;
  const int wrow = wave << 5;

  f32x4 acc[2][4];
  #pragma unroll
  for (int i = 0; i < 2; i++)
    #pragma unroll
    for (int j = 0; j < 4; j++) acc[i][j] = (f32x4){0.f, 0.f, 0.f, 0.f};

  for (int k0 = 0; k0 < K; k0 += 32){
    #pragma unroll
    for (int p = 0; p < 2; p++){
      int row = lr + (p << 6);
      int gm = m0 + row;
      union { u16 h[8]; uint4 v; } pk;
      pk.v = make_uint4(0u, 0u, 0u, 0u);
      if (gm < M){
        if (aF32){
          const float* src = (const float*)Av + (size_t)gm * K + k0 + lkc;
          float4 f0 = *(const float4*)src;
          float4 f1 = *(const float4*)(src + 4);
          pk.h[0] = f2bf(f0.x); pk.h[1] = f2bf(f0.y); pk.h[2] = f2bf(f0.z); pk.h[3] = f2bf(f0.w);
          pk.h[4] = f2bf(f1.x); pk.h[5] = f2bf(f1.y); pk.h[6] = f2bf(f1.z); pk.h[7] = f2bf(f1.w);
        } else {
          pk.v = *(const uint4*)((const u16*)Av + (size_t)gm * K + k0 + lkc);
        }
      }
      *(uint4*)(&lA[row * 40 + lkc]) = pk.v;
    }
    *(uint4*)(&lB[lr * 40 + lkc]) = *(const uint4*)(Bt + (size_t)(n0 + lr) * K + k0 + lkc);
    __syncthreads();
    short8 a0 = *(const short8*)(&lA[(wrow + lm) * 40 + lk]);
    short8 a1 = *(const short8*)(&lA[(wrow + 16 + lm) * 40 + lk]);
    #pragma unroll
    for (int nj = 0; nj < 4; nj++){
      short8 b = *(const short8*)(&lB[(nj * 16 + lm) * 40 + lk]);
      acc[0][nj] = __builtin_amdgcn_mfma_f32_16x16x32_bf16(a0, b, acc[0][nj], 0, 0, 0);
      acc[1][nj] = __builtin_amdgcn_mfma_f32_16x16x32_bf16(a1, b, acc[1][nj], 0, 0, 0);
    }
    __syncthreads();
  }

  #pragma unroll
  for (int mi = 0; mi < 2; mi++)
    #pragma unroll
    for (int r4 = 0; r4 < 4; r4++){
      int row = wrow + mi * 16 + ((lane >> 4) << 2) + r4;
      int gm = m0 + row;
      if (gm < M){
        #pragma unroll
        for (int nj = 0; nj < 4; nj++){
          int gc = n0 + nj * 16 + lm;
          outBf[(size_t)gm * Ntot + gc] = f2bf(acc[mi][nj][r4] + bias[gc]);
        }
      }
    }
}

// ---------- fused edge GEMM: ea[ETOT,384] x [W1e|W2e][384,320] ----------
// 64-row tile, 4 waves (known-good geometry) + register prefetch pipeline:
// tile k+1's global loads are issued before the MFMA phase of tile k, so the
// vmcnt drain at the trailing barrier only pays residual latency.
// Loads are UNCONDITIONAL (no guards, no lambdas) to keep values in VGPRs:
// tail rows read into the adjacent allocated XLR1 region (harmless, masked at
// the epilogue). A-source f32-vs-bf16 is a per-thread base pointer + shift.
__global__ __launch_bounds__(256)
void edge_k(const float* __restrict__ eattr, const u16* __restrict__ loopA16,
            const u16* __restrict__ BtE,     // [320 x 384] bf16
            const int* __restrict__ rowA, const int* __restrict__ colA,
            const u16* __restrict__ XLR1,    // [NN x 512] bf16 = [xl1 | xr1]
            const float* __restrict__ att1,  // [256] f32
            float* __restrict__ logit1,      // [ETOT x 4] f32
            u16* __restrict__ ep2)           // [ETOT x 64] bf16
{
  __shared__ __align__(16) u16 lA[64 * 40];
  __shared__ __align__(16) u16 lB[320 * 40];
  const int tid = threadIdx.x;
  const int lane = tid & 63;
  const int wave = tid >> 6;            // head 0..3
  const int m0 = blockIdx.x * 64;
  const int lm = lane & 15;
  const int lk = (lane >> 4) << 3;
  const int arow = tid >> 2;            // 0..63
  const int akc = (tid & 3) << 3;       // 0,8,16,24

  f32x4 acc[4][5];
  #pragma unroll
  for (int i = 0; i < 4; i++)
    #pragma unroll
    for (int j = 0; j < 5; j++) acc[i][j] = (f32x4){0.f, 0.f, 0.f, 0.f};

  const int gmA = m0 + arow;
  const int isF = (gmA < NE);
  const char* aBase = isF ? (const char*)(eattr + (size_t)gmA * ED)
                          : (const char*)(loopA16 + (size_t)(gmA - NE) * ED);
  const int aSh = isF ? 2 : 1;
  const u16* bBase = BtE + (size_t)arow * ED + akc;

  uint4 pA0, pA1, pB0, pB1, pB2, pB3, pB4;

#define EDGE_ISSUE(K0) \
  { size_t aoff = ((size_t)((K0) + akc)) << aSh; \
    pA0 = *(const uint4*)(aBase + aoff); \
    pA1 = *(const uint4*)(aBase + aoff + 16); \
    const u16* bp = bBase + (K0); \
    pB0 = *(const uint4*)(bp); \
    pB1 = *(const uint4*)(bp + (size_t)64 * ED); \
    pB2 = *(const uint4*)(bp + (size_t)128 * ED); \
    pB3 = *(const uint4*)(bp + (size_t)192 * ED); \
    pB4 = *(const uint4*)(bp + (size_t)256 * ED); }

#define EDGE_STORE \
  { union { u16 h[8]; uint4 v; } pk; \
    if (isF){ \
      const float* f0 = (const float*)&pA0; \
      const float* f1 = (const float*)&pA1; \
      pk.h[0] = f2bf(f0[0]); pk.h[1] = f2bf(f0[1]); pk.h[2] = f2bf(f0[2]); pk.h[3] = f2bf(f0[3]); \
      pk.h[4] = f2bf(f1[0]); pk.h[5] = f2bf(f1[1]); pk.h[6] = f2bf(f1[2]); pk.h[7] = f2bf(f1[3]); \
    } else { pk.v = pA0; } \
    *(uint4*)(&lA[arow * 40 + akc]) = pk.v; \
    *(uint4*)(&lB[(arow      ) * 40 + akc]) = pB0; \
    *(uint4*)(&lB[(arow +  64) * 40 + akc]) = pB1; \
    *(uint4*)(&lB[(arow + 128) * 40 + akc]) = pB2; \
    *(uint4*)(&lB[(arow + 192) * 40 + akc]) = pB3; \
    *(uint4*)(&lB[(arow + 256) * 40 + akc]) = pB4; }

  EDGE_ISSUE(0);
  for (int k0 = 0; k0 < ED; k0 += 32){
    EDGE_STORE;
    __syncthreads();
    if (k0 + 32 < ED) EDGE_ISSUE(k0 + 32);
    short8 a[4];
    #pragma unroll
    for (int mi = 0; mi < 4; mi++) a[mi] = *(const short8*)(&lA[(mi * 16 + lm) * 40 + lk]);
    #pragma unroll
    for (int nj = 0; nj < 4; nj++){
      short8 b = *(const short8*)(&lB[(wave * 64 + nj * 16 + lm) * 40 + lk]);
      #pragma unroll
      for (int mi = 0; mi < 4; mi++)
        acc[mi][nj] = __builtin_amdgcn_mfma_f32_16x16x32_bf16(a[mi], b, acc[mi][nj], 0, 0, 0);
    }
    {
      short8 b = *(const short8*)(&lB[(256 + wave * 16 + lm) * 40 + lk]);
      #pragma unroll
      for (int mi = 0; mi < 4; mi++)
        acc[mi][4] = __builtin_amdgcn_mfma_f32_16x16x32_bf16(a[mi], b, acc[mi][4], 0, 0, 0);
    }
    __syncthreads();
  }
#undef EDGE_ISSUE
#undef EDGE_STORE

  float attc[4];
  #pragma unroll
  for (int nj = 0; nj < 4; nj++) attc[nj] = att1[wave * 64 + nj * 16 + lm];
  const int quad4 = (lane >> 4) << 2;
  #pragma unroll
  for (int mi = 0; mi < 4; mi++)
    #pragma unroll
    for (int r4 = 0; r4 < 4; r4++){
      int e = m0 + mi * 16 + quad4 + r4;
      float partial = 0.f;
      if (e < ETOT){
        int ii = (e < NE) ? rowA[e] : (e - NE);
        int jj = (e < NE) ? colA[e] : (e - NE);
        const u16* xlp = XLR1 + (size_t)jj * 512 + wave * 64;
        const u16* xrp = XLR1 + (size_t)ii * 512 + 256 + wave * 64;
        #pragma unroll
        for (int nj = 0; nj < 4; nj++){
          float v = acc[mi][nj][r4] + bf2f(xlp[nj * 16 + lm]) + bf2f(xrp[nj * 16 + lm]);
          v = (v > 0.f) ? v : 0.2f * v;
          partial += v * attc[nj];
        }
        ep2[(size_t)e * 64 + wave * 16 + lm] = f2bf(acc[mi][4][r4]);
      }
      partial += __shfl_xor(partial, 1);
      partial += __shfl_xor(partial, 2);
      partial += __shfl_xor(partial, 4);
      partial += __shfl_xor(partial, 8);
      if (lm == 0 && e < ETOT) logit1[(size_t)e * 4 + wave] = partial;
    }
}

// ---------- layer-2 logit epilogue: logit2[e] = sum_c att2[c]*leaky0.2(ep2+xl2[j]+xr2[i])
__global__ __launch_bounds__(256) void logit2_k(const int* __restrict__ rowA,
    const int* __restrict__ colA, const u16* __restrict__ ep2,
    const u16* __restrict__ XLR2,   // [NN x 128] = [xl2 | xr2]
    const float* __restrict__ att2, float* __restrict__ logit2)
{
  int e = blockIdx.x * 16 + (threadIdx.x >> 4);
  if (e >= ETOT) return;
  int lm = threadIdx.x & 15;
  int ii = (e < NE) ? rowA[e] : (e - NE);
  int jj = (e < NE) ? colA[e] : (e - NE);
  ushort4 pe = *(const ushort4*)(ep2 + (size_t)e * 64 + lm * 4);
  ushort4 pl = *(const ushort4*)(XLR2 + (size_t)jj * 128 + lm * 4);
  ushort4 pr = *(const ushort4*)(XLR2 + (size_t)ii * 128 + 64 + lm * 4);
  float s = 0.f;
  float v0 = bf2f(pe.x) + bf2f(pl.x) + bf2f(pr.x); v0 = v0 > 0.f ? v0 : 0.2f * v0;
  float v1 = bf2f(pe.y) + bf2f(pl.y) + bf2f(pr.y); v1 = v1 > 0.f ? v1 : 0.2f * v1;
  float v2 = bf2f(pe.z) + bf2f(pl.z) + bf2f(pr.z); v2 = v2 > 0.f ? v2 : 0.2f * v2;
  float v3 = bf2f(pe.w) + bf2f(pl.w) + bf2f(pr.w); v3 = v3 > 0.f ? v3 : 0.2f * v3;
  s = v0 * att2[lm * 4] + v1 * att2[lm * 4 + 1] + v2 * att2[lm * 4 + 2] + v3 * att2[lm * 4 + 3];
  s += __shfl_xor(s, 1);
  s += __shfl_xor(s, 2);
  s += __shfl_xor(s, 4);
  s += __shfl_xor(s, 8);
  if (lm == 0) logit2[e] = s;
}

// ---------- segment softmax + aggregation, layer 1 (H=4, C=64) ----------
__global__ __launch_bounds__(256) void agg1_k(const int* __restrict__ rowPtr,
    const int* __restrict__ rowIdx, const float4* __restrict__ lg4,
    const u16* __restrict__ XL1, int xstride, const int* __restrict__ colA,
    const float* __restrict__ bias1, u16* __restrict__ H1)
{
  int node = blockIdx.x * 4 + (threadIdx.x >> 6);
  if (node >= NN) return;
  int lane = threadIdx.x & 63;
  int p0 = rowPtr[node], deg = rowPtr[node + 1] - p0;
  float4 sl = lg4[NE + node];
  float m0 = sl.x, m1 = sl.y, m2 = sl.z, m3 = sl.w;
  for (int t = lane; t < deg; t += 64){
    float4 l = lg4[rowIdx[p0 + t]];
    m0 = fmaxf(m0, l.x); m1 = fmaxf(m1, l.y); m2 = fmaxf(m2, l.z); m3 = fmaxf(m3, l.w);
  }
  #pragma unroll
  for (int off = 32; off > 0; off >>= 1){
    m0 = fmaxf(m0, __shfl_xor(m0, off));
    m1 = fmaxf(m1, __shfl_xor(m1, off));
    m2 = fmaxf(m2, __shfl_xor(m2, off));
    m3 = fmaxf(m3, __shfl_xor(m3, off));
  }
  float d0, d1, d2, d3, a0, a1, a2, a3;
  {
    float e0 = __expf(sl.x - m0), e1 = __expf(sl.y - m1), e2 = __expf(sl.z - m2), e3 = __expf(sl.w - m3);
    d0 = e0; d1 = e1; d2 = e2; d3 = e3;
    const u16* xp = XL1 + (size_t)node * xstride;
    a0 = e0 * bf2f(xp[lane]); a1 = e1 * bf2f(xp[64 + lane]);
    a2 = e2 * bf2f(xp[128 + lane]); a3 = e3 * bf2f(xp[192 + lane]);
  }
  for (int t = 0; t < deg; t++){
    int e = rowIdx[p0 + t];
    float4 l = lg4[e];
    int j = colA[e];
    float e0 = __expf(l.x - m0), e1 = __expf(l.y - m1), e2 = __expf(l.z - m2), e3 = __expf(l.w - m3);
    d0 += e0; d1 += e1; d2 += e2; d3 += e3;
    const u16* xp = XL1 + (size_t)j * xstride;
    a0 += e0 * bf2f(xp[lane]); a1 += e1 * bf2f(xp[64 + lane]);
    a2 += e2 * bf2f(xp[128 + lane]); a3 += e3 * bf2f(xp[192 + lane]);
  }
  float v0 = a0 / d0 + bias1[lane];
  float v1 = a1 / d1 + bias1[64 + lane];
  float v2 = a2 / d2 + bias1[128 + lane];
  float v3 = a3 / d3 + bias1[192 + lane];
  v0 = v0 > 0.f ? v0 : 0.01f * v0;
  v1 = v1 > 0.f ? v1 : 0.01f * v1;
  v2 = v2 > 0.f ? v2 : 0.01f * v2;
  v3 = v3 > 0.f ? v3 : 0.01f * v3;
  u16* hp = H1 + (size_t)node * NH1;
  hp[lane] = f2bf(v0); hp[64 + lane] = f2bf(v1);
  hp[128 + lane] = f2bf(v2); hp[192 + lane] = f2bf(v3);
}

// ---------- layer 2 softmax+agg (H=1, C=64) ----------
__global__ __launch_bounds__(256) void agg2_k(const int* __restrict__ rowPtr,
    const int* __restrict__ rowIdx, const float* __restrict__ lg,
    const u16* __restrict__ XL2, int xstride, const int* __restrict__ colA,
    const float* __restrict__ bias2, float* __restrict__ H2)
{
  int node = blockIdx.x * 4 + (threadIdx.x >> 6);
  if (node >= NN) return;
  int lane = threadIdx.x & 63;
  int p0 = rowPtr[node], deg = rowPtr[node + 1] - p0;
  float sl = lg[NE + node];
  float mx = sl;
  for (int t = lane; t < deg; t += 64) mx = fmaxf(mx, lg[rowIdx[p0 + t]]);
  #pragma unroll
  for (int off = 32; off > 0; off >>= 1) mx = fmaxf(mx, __shfl_xor(mx, off));
  float den = __expf(sl - mx);
  float acc = den * bf2f(XL2[(size_t)node * xstride + lane]);
  for (int t = 0; t < deg; t++){
    int e = rowIdx[p0 + t];
    float ex = __expf(lg[e] - mx);
    den += ex;
    acc += ex * bf2f(XL2[(size_t)colA[e] * xstride + lane]);
  }
  float v = acc / den + bias2[lane];
  v = v > 0.f ? v : 0.01f * v;
  H2[(size_t)node * 64 + lane] = v;
}

// ---------- global max pool + LayerNorm (C=64), 4 waves/block ----------
__global__ __launch_bounds__(256) void poolln_k(const float* __restrict__ H2,
    const float* __restrict__ lng, const float* __restrict__ lnb, float* __restrict__ outGn)
{
  __shared__ float sm[4][64];
  int g = blockIdx.x, w = threadIdx.x >> 6, c = threadIdx.x & 63;
  int beg = (g * NN + NG - 1) / NG;
  int end = ((g + 1) * NN + NG - 1) / NG;
  float m = -3.0e38f;
  for (int n = beg + w; n < end; n += 4) m = fmaxf(m, H2[(size_t)n * 64 + c]);
  sm[w][c] = m;
  __syncthreads();
  if (threadIdx.x < 64){
    m = fmaxf(fmaxf(sm[0][c], sm[1][c]), fmaxf(sm[2][c], sm[3][c]));
    float s = m;
    #pragma unroll
    for (int off = 32; off > 0; off >>= 1) s += __shfl_xor(s, off);
    float mu = s * (1.f / 64.f);
    float d = m - mu;
    float vv = d * d;
    #pragma unroll
    for (int off = 32; off > 0; off >>= 1) vv += __shfl_xor(vv, off);
    float var = vv * (1.f / 64.f);
    outGn[g * 64 + c] = d * rsqrtf(var + 1e-5f) * lng[c] + lnb[c];
  }
}

// ---------- classifier [G,64] @ [64,751] + b ----------
__global__ __launch_bounds__(256) void clf_k(const float* __restrict__ gn,
    const float* __restrict__ W, const float* __restrict__ b, float* __restrict__ outCls)
{
  __shared__ float sg[64];
  int g = blockIdx.x;
  if (threadIdx.x < 64) sg[threadIdx.x] = gn[g * 64 + threadIdx.x];
  __syncthreads();
  for (int o = threadIdx.x; o < NCLS; o += 256){
    float s = b[o];
    #pragma unroll 16
    for (int c = 0; c < 64; c++) s += sg[c] * W[c * NCLS + o];
    outCls[(size_t)g * NCLS + o] = s;
  }
}

extern "C" void kernel_launch(void* const* d_in, const int* in_sizes, int n_in,
                              void* d_out, int out_size, void* d_ws, size_t ws_size,
                              hipStream_t stream)
{
  const float* x     = (const float*)d_in[0];
  const int*   eidx  = (const int*)d_in[1];
  const float* eattr = (const float*)d_in[2];
  const float* W1l = (const float*)d_in[4];
  const float* b1l = (const float*)d_in[5];
  const float* W1r = (const float*)d_in[6];
  const float* b1r = (const float*)d_in[7];
  const float* W1e = (const float*)d_in[8];
  const float* att1 = (const float*)d_in[9];
  const float* bias1 = (const float*)d_in[10];
  const float* W2l = (const float*)d_in[11];
  const float* b2l = (const float*)d_in[12];
  const float* W2r = (const float*)d_in[13];
  const float* b2r = (const float*)d_in[14];
  const float* W2e = (const float*)d_in[15];
  const float* att2 = (const float*)d_in[16];
  const float* bias2 = (const float*)d_in[17];
  const float* lng = (const float*)d_in[18];
  const float* lnb = (const float*)d_in[19];
  const float* clfW = (const float*)d_in[20];
  const float* clfb = (const float*)d_in[21];
  const int* rowA = eidx;        // ei_i (aggregation target)
  const int* colA = eidx + NE;   // ei_j (message source)

  char* w = (char*)d_ws;
  auto alloc = [&](size_t b) -> char* {
    char* p = w; w += (b + 255) & ~(size_t)255; return p;
  };
  u16* W1lrT  = (u16*)alloc((size_t)512 * 512 * 2);   // [512 cols x 512 K]
  u16* BtE    = (u16*)alloc((size_t)320 * ED * 2);    // [W1e|W2e]^T
  u16* W2lrT  = (u16*)alloc((size_t)128 * 256 * 2);
  float* biasLR1 = (float*)alloc(512 * 4);
  float* biasLR2 = (float*)alloc(128 * 4);
  int* degR   = (int*)alloc((size_t)NN * 4);
  int* degC   = (int*)alloc((size_t)NN * 4);
  int* rowPtr = (int*)alloc((size_t)(NN + 1) * 4);
  int* colPtr = (int*)alloc((size_t)(NN + 1) * 4);
  int* rowCur = (int*)alloc((size_t)NN * 4);
  int* colCur = (int*)alloc((size_t)NN * 4);
  int* rowIdx = (int*)alloc((size_t)NE * 4);
  int* colIdx = (int*)alloc((size_t)NE * 4);
  char* loopRegion = alloc((size_t)NN * ED * 2);      // 15.36 MB, reused after edge_k
  u16* loopA16 = (u16*)loopRegion;
  u16* XLR1   = (u16*)alloc((size_t)NN * 512 * 2);
  float* logit1 = (float*)alloc((size_t)ETOT * 4 * 4);
  u16* H1     = (u16*)alloc((size_t)NN * NH1 * 2);
  u16* ep2    = (u16*)alloc((size_t)ETOT * 64 * 2);
  // aliased into loopRegion (loopA16's last reader is edge_k):
  u16* XLR2   = (u16*)loopRegion;                               // 5.12 MB
  float* logit2 = (float*)(loopRegion + (size_t)5500928);       // 0.88 MB
  float* H2   = (float*)(loopRegion + (size_t)6553600);         // 5.12 MB

  hipMemsetAsync(degR, 0, (size_t)NN * 4, stream);
  hipMemsetAsync(degC, 0, (size_t)NN * 4, stream);
  hipMemsetAsync(rowCur, 0, (size_t)NN * 4, stream);
  hipMemsetAsync(colCur, 0, (size_t)NN * 4, stream);

  transpose_k<<<(512 * 256 + 255) / 256, 256, 0, stream>>>(W1l, W1lrT, 512, 256);
  transpose_k<<<(512 * 256 + 255) / 256, 256, 0, stream>>>(W1r, W1lrT + (size_t)256 * 512, 512, 256);
  transpose_k<<<(ED * 256 + 255) / 256, 256, 0, stream>>>(W1e, BtE, ED, 256);
  transpose_k<<<(ED * 64 + 255) / 256, 256, 0, stream>>>(W2e, BtE + (size_t)256 * ED, ED, 64);
  transpose_k<<<(256 * 64 + 255) / 256, 256, 0, stream>>>(W2l, W2lrT, 256, 64);
  transpose_k<<<(256 * 64 + 255) / 256, 256, 0, stream>>>(W2r, W2lrT + (size_t)64 * 256, 256, 64);
  concatbias_k<<<3, 256, 0, stream>>>(b1l, b1r, b2l, b2r, biasLR1, biasLR2);

  hist_k<<<(NE + 255) / 256, 256, 0, stream>>>(rowA, colA, degR, degC);
  scan_k<<<1, 256, 0, stream>>>(degR, degC, rowPtr, colPtr);
  scatter_k<<<(NE + 255) / 256, 256, 0, stream>>>(rowA, colA, rowPtr, colPtr,
                                                  rowCur, colCur, rowIdx, colIdx);
  loopattr_k<<<(NN + 3) / 4, 256, 0, stream>>>(colPtr, colIdx, eattr, loopA16);

  // XLR1 = x @ [W1l|W1r] + [b1l|b1r]  -> [NN, 512] bf16
  dim3 gx1((NN + 127) / 128, 8);
  gemm_k<<<gx1, 256, 0, stream>>>(x, 1, W1lrT, NN, 512, 512, biasLR1, XLR1);
  // fused edge GEMM: logit1 + ep2
  edge_k<<<(ETOT + 63) / 64, 256, 0, stream>>>(eattr, loopA16, BtE, rowA, colA,
                                               XLR1, att1, logit1, ep2);
  agg1_k<<<(NN + 3) / 4, 256, 0, stream>>>(rowPtr, rowIdx, (const float4*)logit1,
                                           XLR1, 512, colA, bias1, H1);
  // XLR2 = H1 @ [W2l|W2r] + [b2l|b2r]  -> [NN, 128] bf16
  dim3 gx2((NN + 127) / 128, 2);
  gemm_k<<<gx2, 256, 0, stream>>>(H1, 0, W2lrT, NN, 256, 128, biasLR2, XLR2);
  logit2_k<<<(ETOT + 15) / 16, 256, 0, stream>>>(rowA, colA, ep2, XLR2, att2, logit2);
  agg2_k<<<(NN + 3) / 4, 256, 0, stream>>>(rowPtr, rowIdx, logit2, XLR2, 128, colA, bias2, H2);

  float* outCls = (float*)d_out;
  float* outGn  = outCls + (size_t)NG * NCLS;
  poolln_k<<<NG, 256, 0, stream>>>(H2, lng, lnb, outGn);
  clf_k<<<NG, 256, 0, stream>>>(outGn, clfW, clfb, outCls);
}

// Round 5
// 962.741 us; speedup vs baseline: 1.1919x; 1.0045x over previous
//
#include <hip/hip_runtime.h>

#define NN 20000      // nodes
#define NE 200000     // edges
#define NH1 256       // H*C layer1
#define ED 384
#define NG 64
#define NCLS 751
#define ETOT (NE + NN)   // 220000 edges incl self loops

typedef unsigned short u16;
typedef __attribute__((ext_vector_type(8))) short short8;
typedef __attribute__((ext_vector_type(4))) float f32x4;

__device__ __forceinline__ float bf2f(u16 u){
  union { unsigned int i; float f; } v; v.i = ((unsigned int)u) << 16; return v.f;
}
__device__ __forceinline__ u16 f2bf(float f){
  union { float f; unsigned int i; } v; v.f = f;
  return (u16)((v.i + 0x7fffu + ((v.i >> 16) & 1u)) >> 16);
}

// ---------- prep kernels ----------
// transpose + f32->bf16: in [K,N] f32 row-major -> out [N,K] bf16
__global__ void transpose_k(const float* __restrict__ in, u16* __restrict__ out, int K, int N){
  int idx = blockIdx.x * 256 + threadIdx.x;
  if (idx >= K * N) return;
  int k = idx / N, n = idx - k * N;
  out[n * K + k] = f2bf(in[idx]);
}

// straight f32 -> bf16, 8 elems/thread
__global__ void convx_k(const float* __restrict__ in, u16* __restrict__ out, int total8){
  int idx = blockIdx.x * 256 + threadIdx.x;
  if (idx >= total8) return;
  const float4* p = (const float4*)in + (size_t)idx * 2;
  float4 f0 = p[0], f1 = p[1];
  union { u16 h[8]; uint4 v; } pk;
  pk.h[0] = f2bf(f0.x); pk.h[1] = f2bf(f0.y); pk.h[2] = f2bf(f0.z); pk.h[3] = f2bf(f0.w);
  pk.h[4] = f2bf(f1.x); pk.h[5] = f2bf(f1.y); pk.h[6] = f2bf(f1.z); pk.h[7] = f2bf(f1.w);
  ((uint4*)out)[idx] = pk.v;
}

__global__ void concatbias_k(const float* __restrict__ b1l, const float* __restrict__ b1r,
                             const float* __restrict__ b2l, const float* __restrict__ b2r,
                             float* __restrict__ biasLR1, float* __restrict__ biasLR2){
  int i = blockIdx.x * 256 + threadIdx.x;
  if (i < 256) biasLR1[i] = b1l[i];
  else if (i < 512) biasLR1[i] = b1r[i - 256];
  else if (i < 576) biasLR2[i - 512] = b2l[i - 512];
  else if (i < 640) biasLR2[i - 512] = b2r[i - 576];
}

__global__ void hist_k(const int* __restrict__ rowA, const int* __restrict__ colA,
                       int* __restrict__ degR, int* __restrict__ degC){
  int e = blockIdx.x * 256 + threadIdx.x;
  if (e >= NE) return;
  atomicAdd(&degR[rowA[e]], 1);
  atomicAdd(&degC[colA[e]], 1);
}

__global__ void scan_k(const int* __restrict__ degR, const int* __restrict__ degC,
                       int* __restrict__ rowPtr, int* __restrict__ colPtr){
  __shared__ int sR[256], sC[256];
  int t = threadIdx.x;
  const int chunk = (NN + 255) / 256;
  int beg = t * chunk, end = min(beg + chunk, NN);
  int aR = 0, aC = 0;
  for (int i = beg; i < end; i++){ aR += degR[i]; aC += degC[i]; }
  sR[t] = aR; sC[t] = aC;
  __syncthreads();
  for (int off = 1; off < 256; off <<= 1){
    int vR = 0, vC = 0;
    if (t >= off){ vR = sR[t - off]; vC = sC[t - off]; }
    __syncthreads();
    sR[t] += vR; sC[t] += vC;
    __syncthreads();
  }
  int rR = (t == 0) ? 0 : sR[t - 1];
  int rC = (t == 0) ? 0 : sC[t - 1];
  for (int i = beg; i < end; i++){
    rowPtr[i] = rR; rR += degR[i];
    colPtr[i] = rC; rC += degC[i];
  }
  if (t == 255){ rowPtr[NN] = sR[255]; colPtr[NN] = sC[255]; }
}

__global__ void scatter_k(const int* __restrict__ rowA, const int* __restrict__ colA,
                          const int* __restrict__ rowPtr, const int* __restrict__ colPtr,
                          int* __restrict__ rowCur, int* __restrict__ colCur,
                          int* __restrict__ rowIdx, int* __restrict__ colIdx){
  int e = blockIdx.x * 256 + threadIdx.x;
  if (e >= NE) return;
  int r = rowA[e]; int p = atomicAdd(&rowCur[r], 1); rowIdx[rowPtr[r] + p] = e;
  int c = colA[e]; int q = atomicAdd(&colCur[c], 1); colIdx[colPtr[c] + q] = e;
}

// loop_attr[n] = mean over incoming (col) edges of edge_attr -> bf16.
// FUSED: also converts each streamed eattr row to bf16 into ea16[e] (each edge
// appears exactly once in the col-CSR, so every row is converted exactly once).
// Self-loop mean rows land at ea16[NE + node].
__global__ __launch_bounds__(256) void loopattr_k(const int* __restrict__ colPtr,
                                                  const int* __restrict__ colIdx,
                                                  const float* __restrict__ eattr,
                                                  u16* __restrict__ ea16){
  int node = blockIdx.x * 4 + (threadIdx.x >> 6);
  if (node >= NN) return;
  int lane = threadIdx.x & 63;
  int p0 = colPtr[node], deg = colPtr[node + 1] - p0;
  float inv = 1.f / fmaxf((float)deg, 1.f);
  float s[6] = {0.f, 0.f, 0.f, 0.f, 0.f, 0.f};
  for (int t = 0; t < deg; t++){
    int e = colIdx[p0 + t];
    const float* rowp = eattr + (size_t)e * ED;
    u16* wp = ea16 + (size_t)e * ED;
    #pragma unroll
    for (int c0 = 0; c0 < 6; c0++){
      float v = rowp[c0 * 64 + lane];
      s[c0] += v;
      wp[c0 * 64 + lane] = f2bf(v);
    }
  }
  u16* outp = ea16 + (size_t)(NE + node) * ED;
  #pragma unroll
  for (int c0 = 0; c0 < 6; c0++) outp[c0 * 64 + lane] = f2bf(s[c0] * inv);
}

// ---------- node GEMM (bf16 A): C[M,Ntot] = A16[M,K] x B, bf16 out + f32 bias
// Named-scalar register prefetch (proven no-spill): tile k+1 loads issued
// before the MFMA phase of tile k. Loads unconditional; tail rows read into
// the adjacent allocation (harmless, masked at the store).
__global__ __launch_bounds__(256)
void gemm_k(const u16* __restrict__ A16,
            const u16* __restrict__ Bt, int M, int K, int Ntot,
            const float* __restrict__ bias, u16* __restrict__ outBf)
{
  __shared__ __align__(16) u16 lA[128 * 40];
  __shared__ __align__(16) u16 lB[64 * 40];
  const int tid  = threadIdx.x;
  const int lane = tid & 63;
  const int wave = tid >> 6;
  const int m0 = blockIdx.x * 128;
  const int n0 = blockIdx.y * 64;
  const int lr  = tid >> 2;
  const int lkc = (tid & 3) << 3;
  const int lm = lane & 15;
  const int lk = (lane >> 4) << 3;
  const int wrow = wave << 5;

  f32x4 acc[2][4];
  #pragma unroll
  for (int i = 0; i < 2; i++)
    #pragma unroll
    for (int j = 0; j < 4; j++) acc[i][j] = (f32x4){0.f, 0.f, 0.f, 0.f};

  const u16* aB0 = A16 + (size_t)(m0 + lr) * K + lkc;
  const u16* aB1 = A16 + (size_t)(m0 + lr + 64) * K + lkc;
  const u16* bB  = Bt + (size_t)(n0 + lr) * K + lkc;

  uint4 rA0, rA1, rB;

#define GEMM_ISSUE(K0) \
  { rA0 = *(const uint4*)(aB0 + (K0)); \
    rA1 = *(const uint4*)(aB1 + (K0)); \
    rB  = *(const uint4*)(bB  + (K0)); }

  GEMM_ISSUE(0);
  for (int k0 = 0; k0 < K; k0 += 32){
    *(uint4*)(&lA[lr * 40 + lkc]) = rA0;
    *(uint4*)(&lA[(lr + 64) * 40 + lkc]) = rA1;
    *(uint4*)(&lB[lr * 40 + lkc]) = rB;
    __syncthreads();
    if (k0 + 32 < K) GEMM_ISSUE(k0 + 32);
    short8 a0 = *(const short8*)(&lA[(wrow + lm) * 40 + lk]);
    short8 a1 = *(const short8*)(&lA[(wrow + 16 + lm) * 40 + lk]);
    #pragma unroll
    for (int nj = 0; nj < 4; nj++){
      short8 b = *(const short8*)(&lB[(nj * 16 + lm) * 40 + lk]);
      acc[0][nj] = __builtin_amdgcn_mfma_f32_16x16x32_bf16(a0, b, acc[0][nj], 0, 0, 0);
      acc[1][nj] = __builtin_amdgcn_mfma_f32_16x16x32_bf16(a1, b, acc[1][nj], 0, 0, 0);
    }
    __syncthreads();
  }
#undef GEMM_ISSUE

  #pragma unroll
  for (int mi = 0; mi < 2; mi++)
    #pragma unroll
    for (int r4 = 0; r4 < 4; r4++){
      int row = wrow + mi * 16 + ((lane >> 4) << 2) + r4;
      int gm = m0 + row;
      if (gm < M){
        #pragma unroll
        for (int nj = 0; nj < 4; nj++){
          int gc = n0 + nj * 16 + lm;
          outBf[(size_t)gm * Ntot + gc] = f2bf(acc[mi][nj][r4] + bias[gc]);
        }
      }
    }
}

// ---------- fused edge GEMM: ea16[ETOT,384] x [W1e|W2e][384,320] ----------
// A is uniform pre-converted bf16 (no f32 path, no f2bf in staging).
// Named-scalar register prefetch pipeline as in gemm_k.
__global__ __launch_bounds__(256)
void edge_k(const u16* __restrict__ ea16,   // [ETOT x 384] bf16 (edges + self loops)
            const u16* __restrict__ BtE,    // [320 x 384] bf16
            const int* __restrict__ rowA, const int* __restrict__ colA,
            const u16* __restrict__ XLR1,   // [NN x 512] bf16 = [xl1 | xr1]
            const float* __restrict__ att1, // [256] f32
            float* __restrict__ logit1,     // [ETOT x 4] f32
            u16* __restrict__ ep2)          // [ETOT x 64] bf16
{
  __shared__ __align__(16) u16 lA[64 * 40];
  __shared__ __align__(16) u16 lB[320 * 40];
  const int tid = threadIdx.x;
  const int lane = tid & 63;
  const int wave = tid >> 6;            // head 0..3
  const int m0 = blockIdx.x * 64;
  const int lm = lane & 15;
  const int lk = (lane >> 4) << 3;
  const int arow = tid >> 2;            // 0..63
  const int akc = (tid & 3) << 3;       // 0,8,16,24

  f32x4 acc[4][5];
  #pragma unroll
  for (int i = 0; i < 4; i++)
    #pragma unroll
    for (int j = 0; j < 5; j++) acc[i][j] = (f32x4){0.f, 0.f, 0.f, 0.f};

  const int gmA = m0 + arow;
  const u16* aBase = ea16 + (size_t)gmA * ED + akc;   // tail rows read into x16 region: harmless
  const u16* bBase = BtE + (size_t)arow * ED + akc;

  uint4 pA, pB0, pB1, pB2, pB3, pB4;

#define EDGE_ISSUE(K0) \
  { pA  = *(const uint4*)(aBase + (K0)); \
    const u16* bp = bBase + (K0); \
    pB0 = *(const uint4*)(bp); \
    pB1 = *(const uint4*)(bp + (size_t)64 * ED); \
    pB2 = *(const uint4*)(bp + (size_t)128 * ED); \
    pB3 = *(const uint4*)(bp + (size_t)192 * ED); \
    pB4 = *(const uint4*)(bp + (size_t)256 * ED); }

  EDGE_ISSUE(0);
  for (int k0 = 0; k0 < ED; k0 += 32){
    *(uint4*)(&lA[arow * 40 + akc]) = pA;
    *(uint4*)(&lB[(arow      ) * 40 + akc]) = pB0;
    *(uint4*)(&lB[(arow +  64) * 40 + akc]) = pB1;
    *(uint4*)(&lB[(arow + 128) * 40 + akc]) = pB2;
    *(uint4*)(&lB[(arow + 192) * 40 + akc]) = pB3;
    *(uint4*)(&lB[(arow + 256) * 40 + akc]) = pB4;
    __syncthreads();
    if (k0 + 32 < ED) EDGE_ISSUE(k0 + 32);
    short8 a[4];
    #pragma unroll
    for (int mi = 0; mi < 4; mi++) a[mi] = *(const short8*)(&lA[(mi * 16 + lm) * 40 + lk]);
    #pragma unroll
    for (int nj = 0; nj < 4; nj++){
      short8 b = *(const short8*)(&lB[(wave * 64 + nj * 16 + lm) * 40 + lk]);
      #pragma unroll
      for (int mi = 0; mi < 4; mi++)
        acc[mi][nj] = __builtin_amdgcn_mfma_f32_16x16x32_bf16(a[mi], b, acc[mi][nj], 0, 0, 0);
    }
    {
      short8 b = *(const short8*)(&lB[(256 + wave * 16 + lm) * 40 + lk]);
      #pragma unroll
      for (int mi = 0; mi < 4; mi++)
        acc[mi][4] = __builtin_amdgcn_mfma_f32_16x16x32_bf16(a[mi], b, acc[mi][4], 0, 0, 0);
    }
    __syncthreads();
  }
#undef EDGE_ISSUE

  float attc[4];
  #pragma unroll
  for (int nj = 0; nj < 4; nj++) attc[nj] = att1[wave * 64 + nj * 16 + lm];
  const int quad4 = (lane >> 4) << 2;
  #pragma unroll
  for (int mi = 0; mi < 4; mi++)
    #pragma unroll
    for (int r4 = 0; r4 < 4; r4++){
      int e = m0 + mi * 16 + quad4 + r4;
      float partial = 0.f;
      if (e < ETOT){
        int ii = (e < NE) ? rowA[e] : (e - NE);
        int jj = (e < NE) ? colA[e] : (e - NE);
        const u16* xlp = XLR1 + (size_t)jj * 512 + wave * 64;
        const u16* xrp = XLR1 + (size_t)ii * 512 + 256 + wave * 64;
        #pragma unroll
        for (int nj = 0; nj < 4; nj++){
          float v = acc[mi][nj][r4] + bf2f(xlp[nj * 16 + lm]) + bf2f(xrp[nj * 16 + lm]);
          v = (v > 0.f) ? v : 0.2f * v;
          partial += v * attc[nj];
        }
        ep2[(size_t)e * 64 + wave * 16 + lm] = f2bf(acc[mi][4][r4]);
      }
      partial += __shfl_xor(partial, 1);
      partial += __shfl_xor(partial, 2);
      partial += __shfl_xor(partial, 4);
      partial += __shfl_xor(partial, 8);
      if (lm == 0 && e < ETOT) logit1[(size_t)e * 4 + wave] = partial;
    }
}

// ---------- layer-2 logit epilogue: logit2[e] = sum_c att2[c]*leaky0.2(ep2+xl2[j]+xr2[i])
__global__ __launch_bounds__(256) void logit2_k(const int* __restrict__ rowA,
    const int* __restrict__ colA, const u16* __restrict__ ep2,
    const u16* __restrict__ XLR2,   // [NN x 128] = [xl2 | xr2]
    const float* __restrict__ att2, float* __restrict__ logit2)
{
  int e = blockIdx.x * 16 + (threadIdx.x >> 4);
  if (e >= ETOT) return;
  int lm = threadIdx.x & 15;
  int ii = (e < NE) ? rowA[e] : (e - NE);
  int jj = (e < NE) ? colA[e] : (e - NE);
  ushort4 pe = *(const ushort4*)(ep2 + (size_t)e * 64 + lm * 4);
  ushort4 pl = *(const ushort4*)(XLR2 + (size_t)jj * 128 + lm * 4);
  ushort4 pr = *(const ushort4*)(XLR2 + (size_t)ii * 128 + 64 + lm * 4);
  float s = 0.f;
  float v0 = bf2f(pe.x) + bf2f(pl.x) + bf2f(pr.x); v0 = v0 > 0.f ? v0 : 0.2f * v0;
  float v1 = bf2f(pe.y) + bf2f(pl.y) + bf2f(pr.y); v1 = v1 > 0.f ? v1 : 0.2f * v1;
  float v2 = bf2f(pe.z) + bf2f(pl.z) + bf2f(pr.z); v2 = v2 > 0.f ? v2 : 0.2f * v2;
  float v3 = bf2f(pe.w) + bf2f(pl.w) + bf2f(pr.w); v3 = v3 > 0.f ? v3 : 0.2f * v3;
  s = v0 * att2[lm * 4] + v1 * att2[lm * 4 + 1] + v2 * att2[lm * 4 + 2] + v3 * att2[lm * 4 + 3];
  s += __shfl_xor(s, 1);
  s += __shfl_xor(s, 2);
  s += __shfl_xor(s, 4);
  s += __shfl_xor(s, 8);
  if (lm == 0) logit2[e] = s;
}

// ---------- segment softmax + aggregation, layer 1 (H=4, C=64) ----------
// Serial edge loop unrolled x2: two independent gather chains in flight.
__global__ __launch_bounds__(256) void agg1_k(const int* __restrict__ rowPtr,
    const int* __restrict__ rowIdx, const float4* __restrict__ lg4,
    const u16* __restrict__ XL1, int xstride, const int* __restrict__ colA,
    const float* __restrict__ bias1, u16* __restrict__ H1)
{
  int node = blockIdx.x * 4 + (threadIdx.x >> 6);
  if (node >= NN) return;
  int lane = threadIdx.x & 63;
  int p0 = rowPtr[node], deg = rowPtr[node + 1] - p0;
  float4 sl = lg4[NE + node];
  float m0 = sl.x, m1 = sl.y, m2 = sl.z, m3 = sl.w;
  for (int t = lane; t < deg; t += 64){
    float4 l = lg4[rowIdx[p0 + t]];
    m0 = fmaxf(m0, l.x); m1 = fmaxf(m1, l.y); m2 = fmaxf(m2, l.z); m3 = fmaxf(m3, l.w);
  }
  #pragma unroll
  for (int off = 32; off > 0; off >>= 1){
    m0 = fmaxf(m0, __shfl_xor(m0, off));
    m1 = fmaxf(m1, __shfl_xor(m1, off));
    m2 = fmaxf(m2, __shfl_xor(m2, off));
    m3 = fmaxf(m3, __shfl_xor(m3, off));
  }
  float d0, d1, d2, d3, a0, a1, a2, a3;
  {
    float e0 = __expf(sl.x - m0), e1 = __expf(sl.y - m1), e2 = __expf(sl.z - m2), e3 = __expf(sl.w - m3);
    d0 = e0; d1 = e1; d2 = e2; d3 = e3;
    const u16* xp = XL1 + (size_t)node * xstride;
    a0 = e0 * bf2f(xp[lane]); a1 = e1 * bf2f(xp[64 + lane]);
    a2 = e2 * bf2f(xp[128 + lane]); a3 = e3 * bf2f(xp[192 + lane]);
  }
  int t = 0;
  for (; t + 1 < deg; t += 2){
    int eA = rowIdx[p0 + t];
    int eB = rowIdx[p0 + t + 1];
    float4 lA_ = lg4[eA];
    float4 lB_ = lg4[eB];
    int jA = colA[eA];
    int jB = colA[eB];
    const u16* xa = XL1 + (size_t)jA * xstride;
    const u16* xb = XL1 + (size_t)jB * xstride;
    float eA0 = __expf(lA_.x - m0), eA1 = __expf(lA_.y - m1), eA2 = __expf(lA_.z - m2), eA3 = __expf(lA_.w - m3);
    float eB0 = __expf(lB_.x - m0), eB1 = __expf(lB_.y - m1), eB2 = __expf(lB_.z - m2), eB3 = __expf(lB_.w - m3);
    d0 += eA0 + eB0; d1 += eA1 + eB1; d2 += eA2 + eB2; d3 += eA3 + eB3;
    a0 += eA0 * bf2f(xa[lane])       + eB0 * bf2f(xb[lane]);
    a1 += eA1 * bf2f(xa[64 + lane])  + eB1 * bf2f(xb[64 + lane]);
    a2 += eA2 * bf2f(xa[128 + lane]) + eB2 * bf2f(xb[128 + lane]);
    a3 += eA3 * bf2f(xa[192 + lane]) + eB3 * bf2f(xb[192 + lane]);
  }
  if (t < deg){
    int e = rowIdx[p0 + t];
    float4 l = lg4[e];
    int j = colA[e];
    float e0 = __expf(l.x - m0), e1 = __expf(l.y - m1), e2 = __expf(l.z - m2), e3 = __expf(l.w - m3);
    d0 += e0; d1 += e1; d2 += e2; d3 += e3;
    const u16* xp = XL1 + (size_t)j * xstride;
    a0 += e0 * bf2f(xp[lane]); a1 += e1 * bf2f(xp[64 + lane]);
    a2 += e2 * bf2f(xp[128 + lane]); a3 += e3 * bf2f(xp[192 + lane]);
  }
  float v0 = a0 / d0 + bias1[lane];
  float v1 = a1 / d1 + bias1[64 + lane];
  float v2 = a2 / d2 + bias1[128 + lane];
  float v3 = a3 / d3 + bias1[192 + lane];
  v0 = v0 > 0.f ? v0 : 0.01f * v0;
  v1 = v1 > 0.f ? v1 : 0.01f * v1;
  v2 = v2 > 0.f ? v2 : 0.01f * v2;
  v3 = v3 > 0.f ? v3 : 0.01f * v3;
  u16* hp = H1 + (size_t)node * NH1;
  hp[lane] = f2bf(v0); hp[64 + lane] = f2bf(v1);
  hp[128 + lane] = f2bf(v2); hp[192 + lane] = f2bf(v3);
}

// ---------- layer 2 softmax+agg (H=1, C=64), unrolled x2 ----------
__global__ __launch_bounds__(256) void agg2_k(const int* __restrict__ rowPtr,
    const int* __restrict__ rowIdx, const float* __restrict__ lg,
    const u16* __restrict__ XL2, int xstride, const int* __restrict__ colA,
    const float* __restrict__ bias2, float* __restrict__ H2)
{
  int node = blockIdx.x * 4 + (threadIdx.x >> 6);
  if (node >= NN) return;
  int lane = threadIdx.x & 63;
  int p0 = rowPtr[node], deg = rowPtr[node + 1] - p0;
  float sl = lg[NE + node];
  float mx = sl;
  for (int t = lane; t < deg; t += 64) mx = fmaxf(mx, lg[rowIdx[p0 + t]]);
  #pragma unroll
  for (int off = 32; off > 0; off >>= 1) mx = fmaxf(mx, __shfl_xor(mx, off));
  float den = __expf(sl - mx);
  float acc = den * bf2f(XL2[(size_t)node * xstride + lane]);
  int t = 0;
  for (; t + 1 < deg; t += 2){
    int eA = rowIdx[p0 + t];
    int eB = rowIdx[p0 + t + 1];
    float exA = __expf(lg[eA] - mx);
    float exB = __expf(lg[eB] - mx);
    int jA = colA[eA];
    int jB = colA[eB];
    den += exA + exB;
    acc += exA * bf2f(XL2[(size_t)jA * xstride + lane])
         + exB * bf2f(XL2[(size_t)jB * xstride + lane]);
  }
  if (t < deg){
    int e = rowIdx[p0 + t];
    float ex = __expf(lg[e] - mx);
    den += ex;
    acc += ex * bf2f(XL2[(size_t)colA[e] * xstride + lane]);
  }
  float v = acc / den + bias2[lane];
  v = v > 0.f ? v : 0.01f * v;
  H2[(size_t)node * 64 + lane] = v;
}

// ---------- global max pool + LayerNorm (C=64), 4 waves/block ----------
__global__ __launch_bounds__(256) void poolln_k(const float* __restrict__ H2,
    const float* __restrict__ lng, const float* __restrict__ lnb, float* __restrict__ outGn)
{
  __shared__ float sm[4][64];
  int g = blockIdx.x, w = threadIdx.x >> 6, c = threadIdx.x & 63;
  int beg = (g * NN + NG - 1) / NG;
  int end = ((g + 1) * NN + NG - 1) / NG;
  float m = -3.0e38f;
  for (int n = beg + w; n < end; n += 4) m = fmaxf(m, H2[(size_t)n * 64 + c]);
  sm[w][c] = m;
  __syncthreads();
  if (threadIdx.x < 64){
    m = fmaxf(fmaxf(sm[0][c], sm[1][c]), fmaxf(sm[2][c], sm[3][c]));
    float s = m;
    #pragma unroll
    for (int off = 32; off > 0; off >>= 1) s += __shfl_xor(s, off);
    float mu = s * (1.f / 64.f);
    float d = m - mu;
    float vv = d * d;
    #pragma unroll
    for (int off = 32; off > 0; off >>= 1) vv += __shfl_xor(vv, off);
    float var = vv * (1.f / 64.f);
    outGn[g * 64 + c] = d * rsqrtf(var + 1e-5f) * lng[c] + lnb[c];
  }
}

// ---------- classifier [G,64] @ [64,751] + b ----------
__global__ __launch_bounds__(256) void clf_k(const float* __restrict__ gn,
    const float* __restrict__ W, const float* __restrict__ b, float* __restrict__ outCls)
{
  __shared__ float sg[64];
  int g = blockIdx.x;
  if (threadIdx.x < 64) sg[threadIdx.x] = gn[g * 64 + threadIdx.x];
  __syncthreads();
  for (int o = threadIdx.x; o < NCLS; o += 256){
    float s = b[o];
    #pragma unroll 16
    for (int c = 0; c < 64; c++) s += sg[c] * W[c * NCLS + o];
    outCls[(size_t)g * NCLS + o] = s;
  }
}

extern "C" void kernel_launch(void* const* d_in, const int* in_sizes, int n_in,
                              void* d_out, int out_size, void* d_ws, size_t ws_size,
                              hipStream_t stream)
{
  const float* x     = (const float*)d_in[0];
  const int*   eidx  = (const int*)d_in[1];
  const float* eattr = (const float*)d_in[2];
  const float* W1l = (const float*)d_in[4];
  const float* b1l = (const float*)d_in[5];
  const float* W1r = (const float*)d_in[6];
  const float* b1r = (const float*)d_in[7];
  const float* W1e = (const float*)d_in[8];
  const float* att1 = (const float*)d_in[9];
  const float* bias1 = (const float*)d_in[10];
  const float* W2l = (const float*)d_in[11];
  const float* b2l = (const float*)d_in[12];
  const float* W2r = (const float*)d_in[13];
  const float* b2r = (const float*)d_in[14];
  const float* W2e = (const float*)d_in[15];
  const float* att2 = (const float*)d_in[16];
  const float* bias2 = (const float*)d_in[17];
  const float* lng = (const float*)d_in[18];
  const float* lnb = (const float*)d_in[19];
  const float* clfW = (const float*)d_in[20];
  const float* clfb = (const float*)d_in[21];
  const int* rowA = eidx;        // ei_i (aggregation target)
  const int* colA = eidx + NE;   // ei_j (message source)

  char* w = (char*)d_ws;
  auto alloc = [&](size_t b) -> char* {
    char* p = w; w += (b + 255) & ~(size_t)255; return p;
  };
  u16* W1lrT  = (u16*)alloc((size_t)512 * 512 * 2);   // [512 cols x 512 K]
  u16* BtE    = (u16*)alloc((size_t)320 * ED * 2);    // [W1e|W2e]^T
  u16* W2lrT  = (u16*)alloc((size_t)128 * 256 * 2);
  float* biasLR1 = (float*)alloc(512 * 4);
  float* biasLR2 = (float*)alloc(128 * 4);
  int* degR   = (int*)alloc((size_t)NN * 4);
  int* degC   = (int*)alloc((size_t)NN * 4);
  int* rowPtr = (int*)alloc((size_t)(NN + 1) * 4);
  int* colPtr = (int*)alloc((size_t)(NN + 1) * 4);
  int* rowCur = (int*)alloc((size_t)NN * 4);
  int* colCur = (int*)alloc((size_t)NN * 4);
  int* rowIdx = (int*)alloc((size_t)NE * 4);
  int* colIdx = (int*)alloc((size_t)NE * 4);
  u16* ea16   = (u16*)alloc((size_t)ETOT * ED * 2);   // 169 MB: bf16 edges + self loops
  u16* x16    = (u16*)alloc((size_t)NN * 512 * 2);    // bf16 x (also absorbs edge_k tail OOB reads)
  u16* XLR1   = (u16*)alloc((size_t)NN * 512 * 2);
  float* logit1 = (float*)alloc((size_t)ETOT * 4 * 4);
  u16* H1     = (u16*)alloc((size_t)NN * NH1 * 2);
  u16* ep2    = (u16*)alloc((size_t)ETOT * 64 * 2);
  // aliased into ea16 (ea16's last reader is edge_k):
  u16* XLR2   = (u16*)ea16;                                  // 5.12 MB
  float* logit2 = (float*)((char*)ea16 + (size_t)5500928);   // 0.88 MB
  float* H2   = (float*)((char*)ea16 + (size_t)6553600);     // 5.12 MB

  hipMemsetAsync(degR, 0, (size_t)NN * 4, stream);
  hipMemsetAsync(degC, 0, (size_t)NN * 4, stream);
  hipMemsetAsync(rowCur, 0, (size_t)NN * 4, stream);
  hipMemsetAsync(colCur, 0, (size_t)NN * 4, stream);

  transpose_k<<<(512 * 256 + 255) / 256, 256, 0, stream>>>(W1l, W1lrT, 512, 256);
  transpose_k<<<(512 * 256 + 255) / 256, 256, 0, stream>>>(W1r, W1lrT + (size_t)256 * 512, 512, 256);
  transpose_k<<<(ED * 256 + 255) / 256, 256, 0, stream>>>(W1e, BtE, ED, 256);
  transpose_k<<<(ED * 64 + 255) / 256, 256, 0, stream>>>(W2e, BtE + (size_t)256 * ED, ED, 64);
  transpose_k<<<(256 * 64 + 255) / 256, 256, 0, stream>>>(W2l, W2lrT, 256, 64);
  transpose_k<<<(256 * 64 + 255) / 256, 256, 0, stream>>>(W2r, W2lrT + (size_t)64 * 256, 256, 64);
  concatbias_k<<<3, 256, 0, stream>>>(b1l, b1r, b2l, b2r, biasLR1, biasLR2);
  convx_k<<<(NN * 512 / 8 + 255) / 256, 256, 0, stream>>>(x, x16, NN * 512 / 8);

  hist_k<<<(NE + 255) / 256, 256, 0, stream>>>(rowA, colA, degR, degC);
  scan_k<<<1, 256, 0, stream>>>(degR, degC, rowPtr, colPtr);
  scatter_k<<<(NE + 255) / 256, 256, 0, stream>>>(rowA, colA, rowPtr, colPtr,
                                                  rowCur, colCur, rowIdx, colIdx);
  loopattr_k<<<(NN + 3) / 4, 256, 0, stream>>>(colPtr, colIdx, eattr, ea16);

  // XLR1 = x @ [W1l|W1r] + [b1l|b1r]  -> [NN, 512] bf16
  dim3 gx1((NN + 127) / 128, 8);
  gemm_k<<<gx1, 256, 0, stream>>>(x16, W1lrT, NN, 512, 512, biasLR1, XLR1);
  // fused edge GEMM: logit1 + ep2
  edge_k<<<(ETOT + 63) / 64, 256, 0, stream>>>(ea16, BtE, rowA, colA,
                                               XLR1, att1, logit1, ep2);
  agg1_k<<<(NN + 3) / 4, 256, 0, stream>>>(rowPtr, rowIdx, (const float4*)logit1,
                                           XLR1, 512, colA, bias1, H1);
  // XLR2 = H1 @ [W2l|W2r] + [b2l|b2r]  -> [NN, 128] bf16
  dim3 gx2((NN + 127) / 128, 2);
  gemm_k<<<gx2, 256, 0, stream>>>(H1, W2lrT, NN, 256, 128, biasLR2, XLR2);
  logit2_k<<<(ETOT + 15) / 16, 256, 0, stream>>>(rowA, colA, ep2, XLR2, att2, logit2);
  agg2_k<<<(NN + 3) / 4, 256, 0, stream>>>(rowPtr, rowIdx, logit2, XLR2, 128, colA, bias2, H2);

  float* outCls = (float*)d_out;
  float* outGn  = outCls + (size_t)NG * NCLS;
  poolln_k<<<NG, 256, 0, stream>>>(H2, lng, lnb, outGn);
  clf_k<<<NG, 256, 0, stream>>>(outGn, clfW, clfb, outCls);
}